// Round 1
// baseline (1168.803 us; speedup 1.0000x reference)
//
#include <hip/hip_runtime.h>
#include <stdint.h>

// Transformer block, fp32 in/out, internally bf16x2-split MFMA (hi+lo, 3 products)
// for near-fp32 accuracy (~1e-5 abs) on the matrix pipe. MI355X / gfx950.

#define DM    1024
#define SEQ   2048
#define HEADS 16
#define DEPTH 64
#define DFF   4096
#define MROWS 4096   // B*S

typedef __bf16 bf16x8 __attribute__((ext_vector_type(8)));
typedef float  f32x4  __attribute__((ext_vector_type(4)));
typedef float  f32x16 __attribute__((ext_vector_type(16)));
typedef unsigned short u16;

__device__ __forceinline__ u16 f2bf(float f) {
  uint32_t u = __float_as_uint(f);
  u += 0x7fffu + ((u >> 16) & 1u);        // RNE; inputs are finite, no NaN handling needed
  return (u16)(u >> 16);
}
__device__ __forceinline__ float bf2f(u16 h) {
  return __uint_as_float(((uint32_t)h) << 16);
}

__device__ __forceinline__ void gload_lds16(const u16* g, u16* l) {
  __builtin_amdgcn_global_load_lds(
      (const __attribute__((address_space(1))) uint32_t*)g,
      (__attribute__((address_space(3))) uint32_t*)l, 16, 0, 0);
}

// ---------------- split fp32 -> bf16 hi/lo (vectorized, G13) ----------------
__global__ void k_split(const float* __restrict__ x, u16* __restrict__ hi,
                        u16* __restrict__ lo, int n4) {
  int i = blockIdx.x * 256 + threadIdx.x;
  if (i >= n4) return;
  float4 v = reinterpret_cast<const float4*>(x)[i];
  ushort4 h, l;
  h.x = f2bf(v.x); l.x = f2bf(v.x - bf2f(h.x));
  h.y = f2bf(v.y); l.y = f2bf(v.y - bf2f(h.y));
  h.z = f2bf(v.z); l.z = f2bf(v.z - bf2f(h.z));
  h.w = f2bf(v.w); l.w = f2bf(v.w - bf2f(h.w));
  reinterpret_cast<ushort4*>(hi)[i] = h;
  reinterpret_cast<ushort4*>(lo)[i] = l;
}

// ---------------- transpose + split: in[K][N] fp32 -> out[N][K] bf16 hi/lo ----------------
__global__ void k_tsplit(const float* __restrict__ in, u16* __restrict__ oh,
                         u16* __restrict__ ol, int K, int N) {
  __shared__ float t[32][33];
  const int tx = threadIdx.x & 31, ty = threadIdx.x >> 5;
  const int c0 = blockIdx.x * 32, r0 = blockIdx.y * 32;
  #pragma unroll
  for (int i = 0; i < 4; i++)
    t[ty + 8 * i][tx] = in[(size_t)(r0 + ty + 8 * i) * N + c0 + tx];
  __syncthreads();
  #pragma unroll
  for (int i = 0; i < 4; i++) {
    const int n = c0 + ty + 8 * i, k = r0 + tx;
    const float v = t[tx][ty + 8 * i];
    const u16 h = f2bf(v);
    oh[(size_t)n * K + k] = h;
    ol[(size_t)n * K + k] = f2bf(v - bf2f(h));
  }
}

// ---------------- split GEMM: C = A[M,K] @ B^T[N,K] + bias, bf16x2 operands ----------------
// 128x128 tile, BK=32, 4 waves, wave tile 64x64 = 2x2 of mfma_f32_32x32x16_bf16.
// LDS tiles [128][32] bf16 with in-row 16B swizzle ^((row&3)<<4) (source pre-swizzled
// for linear global_load_lds dest; reads apply the same XOR -> at the b128 BW floor).
enum { EPI_QK = 0, EPI_VT = 1, EPI_RESID = 2, EPI_RELU = 3 };

__device__ __forceinline__ void stage128x32(const u16* __restrict__ src, int row0,
                                            int K, int k0, u16* ldsbase, int tid) {
  const int w = tid >> 6;
  #pragma unroll
  for (int i = 0; i < 2; i++) {
    const int c = i * 256 + tid;
    const int r = c >> 2;
    const int q = (c & 3) ^ (r & 3);   // inverse-swizzled source (rule 21)
    gload_lds16(src + (size_t)(row0 + r) * K + k0 + q * 8,
                ldsbase + i * 2048 + w * 512);
  }
}

template <int EPI>
__global__ __launch_bounds__(256, 2)
void k_gemm(const u16* __restrict__ Ahi, const u16* __restrict__ Alo,
            const u16* __restrict__ Bhi, const u16* __restrict__ Blo,
            const float* __restrict__ bias, int M, int N, int K,
            float* __restrict__ outf, const float* __restrict__ resid,
            u16* __restrict__ ohi, u16* __restrict__ olo) {
  __shared__ u16 lds[16384];   // Ahi | Alo | Bhi | Blo, each 128x32
  const int tid = threadIdx.x;
  const int lane = tid & 63;
  const int w = tid >> 6, wr = w >> 1, wc = w & 1;
  const int n0 = blockIdx.x * 128, m0 = blockIdx.y * 128;
  const int r5 = lane & 31, g = lane >> 5;

  f32x16 acc[2][2];
  #pragma unroll
  for (int a = 0; a < 2; a++)
    #pragma unroll
    for (int b = 0; b < 2; b++)
      #pragma unroll
      for (int e = 0; e < 16; e++) acc[a][b][e] = 0.f;

  for (int k0 = 0; k0 < K; k0 += 32) {
    stage128x32(Ahi, m0, K, k0, lds,         tid);
    stage128x32(Alo, m0, K, k0, lds + 4096,  tid);
    stage128x32(Bhi, n0, K, k0, lds + 8192,  tid);
    stage128x32(Blo, n0, K, k0, lds + 12288, tid);
    __syncthreads();   // compiler drains vmcnt before s_barrier -> LDS tiles valid

    bf16x8 ah[2][2], al[2][2], bh[2][2], bl[2][2];
    #pragma unroll
    for (int mt = 0; mt < 2; mt++) {
      const int row = wr * 64 + mt * 32 + r5;
      #pragma unroll
      for (int t = 0; t < 2; t++) {
        const int off = row * 32 + (((t * 32 + g * 16) ^ ((row & 3) << 4)) >> 1);
        ah[mt][t] = *reinterpret_cast<const bf16x8*>(&lds[off]);
        al[mt][t] = *reinterpret_cast<const bf16x8*>(&lds[4096 + off]);
      }
    }
    #pragma unroll
    for (int nt = 0; nt < 2; nt++) {
      const int col = wc * 64 + nt * 32 + r5;
      #pragma unroll
      for (int t = 0; t < 2; t++) {
        const int off = col * 32 + (((t * 32 + g * 16) ^ ((col & 3) << 4)) >> 1);
        bh[nt][t] = *reinterpret_cast<const bf16x8*>(&lds[8192 + off]);
        bl[nt][t] = *reinterpret_cast<const bf16x8*>(&lds[12288 + off]);
      }
    }
    #pragma unroll
    for (int mt = 0; mt < 2; mt++)
      #pragma unroll
      for (int nt = 0; nt < 2; nt++)
        #pragma unroll
        for (int t = 0; t < 2; t++) {
          acc[mt][nt] = __builtin_amdgcn_mfma_f32_32x32x16_bf16(ah[mt][t], bh[nt][t], acc[mt][nt], 0, 0, 0);
          acc[mt][nt] = __builtin_amdgcn_mfma_f32_32x32x16_bf16(ah[mt][t], bl[nt][t], acc[mt][nt], 0, 0, 0);
          acc[mt][nt] = __builtin_amdgcn_mfma_f32_32x32x16_bf16(al[mt][t], bh[nt][t], acc[mt][nt], 0, 0, 0);
        }
    __syncthreads();
  }

  // epilogue; 32x32 C layout: col = lane&31, row = (r&3) + 8*(r>>2) + 4*(lane>>5)
  #pragma unroll
  for (int nt = 0; nt < 2; nt++) {
    const int gcol = n0 + wc * 64 + nt * 32 + r5;
    const float bv = bias[gcol];
    #pragma unroll
    for (int mt = 0; mt < 2; mt++) {
      #pragma unroll
      for (int r = 0; r < 16; r++) {
        const int grow = m0 + wr * 64 + mt * 32 + (r & 3) + ((r >> 2) << 3) + (g << 2);
        float v = acc[mt][nt][r] + bv;
        if constexpr (EPI == EPI_RESID) {
          const size_t o = (size_t)grow * N + gcol;
          outf[o] = v + resid[o];
        } else if constexpr (EPI == EPI_RELU) {
          v = fmaxf(v, 0.0f);
          const size_t o = (size_t)grow * N + gcol;
          const u16 h = f2bf(v);
          ohi[o] = h; olo[o] = f2bf(v - bf2f(h));
        } else {
          const int b = grow >> 11, s = grow & 2047;
          const int hh = gcol >> 6, d = gcol & 63;
          size_t o;
          if constexpr (EPI == EPI_QK)
            o = ((size_t)(b * HEADS + hh) * SEQ + s) * DEPTH + d;   // [BH][S][64]
          else
            o = ((size_t)(b * HEADS + hh) * DEPTH + d) * SEQ + s;   // V^T: [BH][64][S]
          const u16 h = f2bf(v);
          ohi[o] = h; olo[o] = f2bf(v - bf2f(h));
        }
      }
    }
  }
}

// ---------------- flash attention, bf16x2-split QK^T and PV ----------------
// 1 block = 4 waves = 64 q rows per (b,h); KV tiles of 64; K/V frags straight from
// L2/L3 (256KB/head-pair, staging would be overhead). P goes through swizzled
// wave-private LDS to convert C-layout -> A-fragment layout.
__global__ __launch_bounds__(256, 2)
void k_attn(const u16* __restrict__ qh, const u16* __restrict__ ql,
            const u16* __restrict__ kh, const u16* __restrict__ kl,
            const u16* __restrict__ vh, const u16* __restrict__ vl,
            u16* __restrict__ ch, u16* __restrict__ cl) {
  __shared__ u16 plds[8192];   // 4 waves x (hi 16x64 | lo 16x64)
  const int tid = threadIdx.x, lane = tid & 63, w = tid >> 6;
  const int l15 = lane & 15, g = lane >> 4;
  const int bh = blockIdx.y;
  const int b = bh >> 4, hd = bh & 15;
  const int q0 = blockIdx.x * 64 + w * 16;
  u16* myp = plds + w * 2048;

  bf16x8 qfh[2], qfl[2];
  #pragma unroll
  for (int t = 0; t < 2; t++) {
    const size_t qi = ((size_t)bh * SEQ + q0 + l15) * DEPTH + t * 32 + g * 8;
    qfh[t] = *reinterpret_cast<const bf16x8*>(&qh[qi]);
    qfl[t] = *reinterpret_cast<const bf16x8*>(&ql[qi]);
  }

  f32x4 o[4];
  #pragma unroll
  for (int dt = 0; dt < 4; dt++)
    #pragma unroll
    for (int e = 0; e < 4; e++) o[dt][e] = 0.f;
  float m_run[4] = {-1e30f, -1e30f, -1e30f, -1e30f};
  float l_run[4] = {0.f, 0.f, 0.f, 0.f};

  for (int kv0 = 0; kv0 < SEQ; kv0 += 64) {
    f32x4 s[4];
    #pragma unroll
    for (int ct = 0; ct < 4; ct++) {
      f32x4 sa;
      #pragma unroll
      for (int e = 0; e < 4; e++) sa[e] = 0.f;
      const size_t kbase = ((size_t)bh * SEQ + kv0 + ct * 16 + l15) * DEPTH;
      #pragma unroll
      for (int t = 0; t < 2; t++) {
        const bf16x8 kfh = *reinterpret_cast<const bf16x8*>(&kh[kbase + t * 32 + g * 8]);
        const bf16x8 kfl = *reinterpret_cast<const bf16x8*>(&kl[kbase + t * 32 + g * 8]);
        sa = __builtin_amdgcn_mfma_f32_16x16x32_bf16(qfh[t], kfh, sa, 0, 0, 0);
        sa = __builtin_amdgcn_mfma_f32_16x16x32_bf16(qfh[t], kfl, sa, 0, 0, 0);
        sa = __builtin_amdgcn_mfma_f32_16x16x32_bf16(qfl[t], kfh, sa, 0, 0, 0);
      }
      s[ct] = sa;
    }

    // online softmax; C layout row = g*4+j, col = ct*16+l15; row-reduce = 4 regs + 4 shfl_xor
    float p[4][4];
    #pragma unroll
    for (int j = 0; j < 4; j++) {
      float mx = fmaxf(fmaxf(s[0][j], s[1][j]), fmaxf(s[2][j], s[3][j])) * 0.125f;
      #pragma unroll
      for (int m = 1; m < 16; m <<= 1) mx = fmaxf(mx, __shfl_xor(mx, m));
      const float mn = fmaxf(m_run[j], mx);
      const float alpha = __expf(m_run[j] - mn);
      m_run[j] = mn;
      float ls = 0.f;
      #pragma unroll
      for (int ct = 0; ct < 4; ct++) {
        const float pv = __expf(s[ct][j] * 0.125f - mn);
        p[ct][j] = pv; ls += pv;
      }
      #pragma unroll
      for (int m = 1; m < 16; m <<= 1) ls += __shfl_xor(ls, m);
      l_run[j] = l_run[j] * alpha + ls;
      #pragma unroll
      for (int dt = 0; dt < 4; dt++) o[dt][j] *= alpha;
    }

    // P -> wave-private LDS (XOR-swizzled: row stride 128B would be a bank pathology, G4)
    #pragma unroll
    for (int ct = 0; ct < 4; ct++)
      #pragma unroll
      for (int j = 0; j < 4; j++) {
        const int R = g * 4 + j;
        const int c = ct * 16 + l15;
        const int e = R * 64 + (c ^ ((R & 7) << 3));
        const float pv = p[ct][j];
        const u16 h = f2bf(pv);
        myp[e] = h;
        myp[1024 + e] = f2bf(pv - bf2f(h));
      }
    asm volatile("s_waitcnt lgkmcnt(0)" ::: "memory");

    bf16x8 pah[2], pal[2];
    #pragma unroll
    for (int t = 0; t < 2; t++) {
      const int e = l15 * 64 + ((t * 32 + g * 8) ^ ((l15 & 7) << 3));
      pah[t] = *reinterpret_cast<const bf16x8*>(&myp[e]);
      pal[t] = *reinterpret_cast<const bf16x8*>(&myp[1024 + e]);
    }

    #pragma unroll
    for (int dt = 0; dt < 4; dt++) {
      const size_t vbase = ((size_t)bh * DEPTH + dt * 16 + l15) * SEQ + kv0;
      #pragma unroll
      for (int t = 0; t < 2; t++) {
        const bf16x8 vfh = *reinterpret_cast<const bf16x8*>(&vh[vbase + t * 32 + g * 8]);
        const bf16x8 vfl = *reinterpret_cast<const bf16x8*>(&vl[vbase + t * 32 + g * 8]);
        o[dt] = __builtin_amdgcn_mfma_f32_16x16x32_bf16(pah[t], vfh, o[dt], 0, 0, 0);
        o[dt] = __builtin_amdgcn_mfma_f32_16x16x32_bf16(pah[t], vfl, o[dt], 0, 0, 0);
        o[dt] = __builtin_amdgcn_mfma_f32_16x16x32_bf16(pal[t], vfh, o[dt], 0, 0, 0);
      }
    }
  }

  #pragma unroll
  for (int j = 0; j < 4; j++) {
    const float inv = 1.0f / l_run[j];
    const int srow = q0 + g * 4 + j;
    #pragma unroll
    for (int dt = 0; dt < 4; dt++) {
      const float v = o[dt][j] * inv;
      const size_t oo = ((size_t)(b * SEQ + srow)) * DM + hd * 64 + dt * 16 + l15;
      const u16 h = f2bf(v);
      ch[oo] = h; cl[oo] = f2bf(v - bf2f(h));
    }
  }
}

// ---------------- LayerNorm (one row per block), optional split output ----------------
template <bool SPLIT>
__global__ __launch_bounds__(256)
void k_ln(const float* __restrict__ x, const float* __restrict__ gam,
          const float* __restrict__ bet, float* __restrict__ outf,
          u16* __restrict__ ohi, u16* __restrict__ olo) {
  const int row = blockIdx.x, tid = threadIdx.x, lane = tid & 63, w = tid >> 6;
  __shared__ float r1[4], r2[4];
  const float4 v = reinterpret_cast<const float4*>(x + (size_t)row * DM)[tid];
  float s = v.x + v.y + v.z + v.w;
  #pragma unroll
  for (int m = 1; m < 64; m <<= 1) s += __shfl_xor(s, m);
  if (lane == 0) r1[w] = s;
  __syncthreads();
  const float mu = (r1[0] + r1[1] + r1[2] + r1[3]) * (1.0f / DM);
  float4 c; c.x = v.x - mu; c.y = v.y - mu; c.z = v.z - mu; c.w = v.w - mu;
  float q = c.x * c.x + c.y * c.y + c.z * c.z + c.w * c.w;
  #pragma unroll
  for (int m = 1; m < 64; m <<= 1) q += __shfl_xor(q, m);
  if (lane == 0) r2[w] = q;
  __syncthreads();
  const float var = (r2[0] + r2[1] + r2[2] + r2[3]) * (1.0f / DM);
  const float rs = rsqrtf(var + 1e-6f);
  const float4 g4 = reinterpret_cast<const float4*>(gam)[tid];
  const float4 b4 = reinterpret_cast<const float4*>(bet)[tid];
  float4 o;
  o.x = c.x * rs * g4.x + b4.x;
  o.y = c.y * rs * g4.y + b4.y;
  o.z = c.z * rs * g4.z + b4.z;
  o.w = c.w * rs * g4.w + b4.w;
  reinterpret_cast<float4*>(outf + (size_t)row * DM)[tid] = o;
  if constexpr (SPLIT) {
    ushort4 h, l;
    h.x = f2bf(o.x); l.x = f2bf(o.x - bf2f(h.x));
    h.y = f2bf(o.y); l.y = f2bf(o.y - bf2f(h.y));
    h.z = f2bf(o.z); l.z = f2bf(o.z - bf2f(h.z));
    h.w = f2bf(o.w); l.w = f2bf(o.w - bf2f(h.w));
    reinterpret_cast<ushort4*>(ohi + (size_t)row * DM)[tid] = h;
    reinterpret_cast<ushort4*>(olo + (size_t)row * DM)[tid] = l;
  }
}

extern "C" void kernel_launch(void* const* d_in, const int* in_sizes, int n_in,
                              void* d_out, int out_size, void* d_ws, size_t ws_size,
                              hipStream_t stream) {
  const float* x   = (const float*)d_in[0];
  const float* wq  = (const float*)d_in[1];
  const float* bq  = (const float*)d_in[2];
  const float* wk  = (const float*)d_in[3];
  const float* bk  = (const float*)d_in[4];
  const float* wv  = (const float*)d_in[5];
  const float* bv  = (const float*)d_in[6];
  const float* wo  = (const float*)d_in[7];
  const float* bo  = (const float*)d_in[8];
  const float* w1  = (const float*)d_in[9];
  const float* b1  = (const float*)d_in[10];
  const float* w2  = (const float*)d_in[11];
  const float* b2  = (const float*)d_in[12];
  const float* g1  = (const float*)d_in[13];
  const float* be1 = (const float*)d_in[14];
  const float* g2  = (const float*)d_in[15];
  const float* be2 = (const float*)d_in[16];
  float* out = (float*)d_out;
  char* ws = (char*)d_ws;
  const size_t MB = (size_t)1 << 20;
  if (ws_size < 160 * MB) return;   // workspace plan needs 160MB (deterministic guard)

  // workspace map (phases reuse regions; every buffer is written before read each call)
  u16* wqt_h = (u16*)(ws + 0 * MB);   u16* wqt_l = (u16*)(ws + 2 * MB);
  u16* wkt_h = (u16*)(ws + 4 * MB);   u16* wkt_l = (u16*)(ws + 6 * MB);
  u16* wvt_h = (u16*)(ws + 8 * MB);   u16* wvt_l = (u16*)(ws + 10 * MB);
  u16* wot_h = (u16*)(ws + 12 * MB);  u16* wot_l = (u16*)(ws + 14 * MB);
  u16* w1t_h = (u16*)(ws + 16 * MB);  u16* w1t_l = (u16*)(ws + 24 * MB);
  u16* w2t_h = (u16*)(ws + 32 * MB);  u16* w2t_l = (u16*)(ws + 40 * MB);
  u16* xh  = (u16*)(ws + 48 * MB);    u16* xl  = (u16*)(ws + 56 * MB);
  u16* qh_ = (u16*)(ws + 64 * MB);    u16* ql_ = (u16*)(ws + 72 * MB);
  u16* kh_ = (u16*)(ws + 80 * MB);    u16* kl_ = (u16*)(ws + 88 * MB);
  u16* vh_ = (u16*)(ws + 96 * MB);    u16* vl_ = (u16*)(ws + 104 * MB);
  u16* hh_ = (u16*)(ws + 48 * MB);    u16* hl_ = (u16*)(ws + 80 * MB);   // reuse x/qkv region
  u16* cth = (u16*)(ws + 112 * MB);   u16* ctl = (u16*)(ws + 120 * MB);
  u16* o1h = (u16*)(ws + 112 * MB);   u16* o1l = (u16*)(ws + 120 * MB);  // reuse ctx region
  float* y   = (float*)(ws + 128 * MB);
  float* o1f = (float*)(ws + 144 * MB);

  // preprocessing: activations split; weights transpose+split to [N][K] bf16 hi/lo
  k_split<<<4096, 256, 0, stream>>>(x, xh, xl, MROWS * DM / 4);
  k_tsplit<<<dim3(32, 32),  256, 0, stream>>>(wq, wqt_h, wqt_l, DM, DM);
  k_tsplit<<<dim3(32, 32),  256, 0, stream>>>(wk, wkt_h, wkt_l, DM, DM);
  k_tsplit<<<dim3(32, 32),  256, 0, stream>>>(wv, wvt_h, wvt_l, DM, DM);
  k_tsplit<<<dim3(32, 32),  256, 0, stream>>>(wo, wot_h, wot_l, DM, DM);
  k_tsplit<<<dim3(128, 32), 256, 0, stream>>>(w1, w1t_h, w1t_l, DM, DFF);
  k_tsplit<<<dim3(32, 128), 256, 0, stream>>>(w2, w2t_h, w2t_l, DFF, DM);

  // QKV projections (epilogue writes head-layout split bf16; V transposed for PV B-operand)
  k_gemm<EPI_QK><<<dim3(8, 32), 256, 0, stream>>>(xh, xl, wqt_h, wqt_l, bq, MROWS, DM, DM, nullptr, nullptr, qh_, ql_);
  k_gemm<EPI_QK><<<dim3(8, 32), 256, 0, stream>>>(xh, xl, wkt_h, wkt_l, bk, MROWS, DM, DM, nullptr, nullptr, kh_, kl_);
  k_gemm<EPI_VT><<<dim3(8, 32), 256, 0, stream>>>(xh, xl, wvt_h, wvt_l, bv, MROWS, DM, DM, nullptr, nullptr, vh_, vl_);

  k_attn<<<dim3(32, 32), 256, 0, stream>>>(qh_, ql_, kh_, kl_, vh_, vl_, cth, ctl);

  // out projection + residual; LN1 (emits fp32 + split for FFN)
  k_gemm<EPI_RESID><<<dim3(8, 32), 256, 0, stream>>>(cth, ctl, wot_h, wot_l, bo, MROWS, DM, DM, y, x, nullptr, nullptr);
  k_ln<true><<<MROWS, 256, 0, stream>>>(y, g1, be1, o1f, o1h, o1l);

  // FFN
  k_gemm<EPI_RELU><<<dim3(32, 32), 256, 0, stream>>>(o1h, o1l, w1t_h, w1t_l, b1, MROWS, DFF, DM, nullptr, nullptr, hh_, hl_);
  k_gemm<EPI_RESID><<<dim3(8, 32), 256, 0, stream>>>(hh_, hl_, w2t_h, w2t_l, b2, MROWS, DM, DFF, y, o1f, nullptr, nullptr);
  k_ln<false><<<MROWS, 256, 0, stream>>>(y, g2, be2, out, nullptr, nullptr);
}

// Round 2
// 900.229 us; speedup vs baseline: 1.2983x; 1.2983x over previous
//
#include <hip/hip_runtime.h>
#include <stdint.h>

// Transformer block, fp32 in/out, internally bf16x2-split MFMA (hi+lo, 3 products)
// for near-fp32 accuracy on the matrix pipe. MI355X / gfx950.
// R2: k_attn rewritten — LDS-staged K/V tiles (shared by 4 waves), double-buffered
// async global_load_lds with counted vmcnt(8) + raw s_barrier (T3-min 2-phase),
// XOR-swizzled tiles so b128 fragment reads sit at the bank floor.

#define DM    1024
#define SEQ   2048
#define HEADS 16
#define DEPTH 64
#define DFF   4096
#define MROWS 4096   // B*S

typedef __bf16 bf16x8 __attribute__((ext_vector_type(8)));
typedef float  f32x4  __attribute__((ext_vector_type(4)));
typedef float  f32x16 __attribute__((ext_vector_type(16)));
typedef unsigned short u16;

__device__ __forceinline__ u16 f2bf(float f) {
  uint32_t u = __float_as_uint(f);
  u += 0x7fffu + ((u >> 16) & 1u);        // RNE; inputs are finite
  return (u16)(u >> 16);
}
__device__ __forceinline__ float bf2f(u16 h) {
  return __uint_as_float(((uint32_t)h) << 16);
}

__device__ __forceinline__ void gload_lds16(const u16* g, u16* l) {
  __builtin_amdgcn_global_load_lds(
      (const __attribute__((address_space(1))) uint32_t*)g,
      (__attribute__((address_space(3))) uint32_t*)l, 16, 0, 0);
}

// ---------------- split fp32 -> bf16 hi/lo (vectorized, G13) ----------------
__global__ void k_split(const float* __restrict__ x, u16* __restrict__ hi,
                        u16* __restrict__ lo, int n4) {
  int i = blockIdx.x * 256 + threadIdx.x;
  if (i >= n4) return;
  float4 v = reinterpret_cast<const float4*>(x)[i];
  ushort4 h, l;
  h.x = f2bf(v.x); l.x = f2bf(v.x - bf2f(h.x));
  h.y = f2bf(v.y); l.y = f2bf(v.y - bf2f(h.y));
  h.z = f2bf(v.z); l.z = f2bf(v.z - bf2f(h.z));
  h.w = f2bf(v.w); l.w = f2bf(v.w - bf2f(h.w));
  reinterpret_cast<ushort4*>(hi)[i] = h;
  reinterpret_cast<ushort4*>(lo)[i] = l;
}

// ---------------- transpose + split: in[K][N] fp32 -> out[N][K] bf16 hi/lo ----------------
__global__ void k_tsplit(const float* __restrict__ in, u16* __restrict__ oh,
                         u16* __restrict__ ol, int K, int N) {
  __shared__ float t[32][33];
  const int tx = threadIdx.x & 31, ty = threadIdx.x >> 5;
  const int c0 = blockIdx.x * 32, r0 = blockIdx.y * 32;
  #pragma unroll
  for (int i = 0; i < 4; i++)
    t[ty + 8 * i][tx] = in[(size_t)(r0 + ty + 8 * i) * N + c0 + tx];
  __syncthreads();
  #pragma unroll
  for (int i = 0; i < 4; i++) {
    const int n = c0 + ty + 8 * i, k = r0 + tx;
    const float v = t[tx][ty + 8 * i];
    const u16 h = f2bf(v);
    oh[(size_t)n * K + k] = h;
    ol[(size_t)n * K + k] = f2bf(v - bf2f(h));
  }
}

// ---------------- split GEMM: C = A[M,K] @ B^T[N,K] + bias, bf16x2 operands ----------------
enum { EPI_QK = 0, EPI_VT = 1, EPI_RESID = 2, EPI_RELU = 3 };

__device__ __forceinline__ void stage128x32(const u16* __restrict__ src, int row0,
                                            int K, int k0, u16* ldsbase, int tid) {
  const int w = tid >> 6;
  #pragma unroll
  for (int i = 0; i < 2; i++) {
    const int c = i * 256 + tid;
    const int r = c >> 2;
    const int q = (c & 3) ^ (r & 3);   // inverse-swizzled source (rule 21)
    gload_lds16(src + (size_t)(row0 + r) * K + k0 + q * 8,
                ldsbase + i * 2048 + w * 512);
  }
}

template <int EPI>
__global__ __launch_bounds__(256, 2)
void k_gemm(const u16* __restrict__ Ahi, const u16* __restrict__ Alo,
            const u16* __restrict__ Bhi, const u16* __restrict__ Blo,
            const float* __restrict__ bias, int M, int N, int K,
            float* __restrict__ outf, const float* __restrict__ resid,
            u16* __restrict__ ohi, u16* __restrict__ olo) {
  __shared__ u16 lds[16384];   // Ahi | Alo | Bhi | Blo, each 128x32
  const int tid = threadIdx.x;
  const int lane = tid & 63;
  const int w = tid >> 6, wr = w >> 1, wc = w & 1;
  const int n0 = blockIdx.x * 128, m0 = blockIdx.y * 128;
  const int r5 = lane & 31, g = lane >> 5;

  f32x16 acc[2][2];
  #pragma unroll
  for (int a = 0; a < 2; a++)
    #pragma unroll
    for (int b = 0; b < 2; b++)
      #pragma unroll
      for (int e = 0; e < 16; e++) acc[a][b][e] = 0.f;

  for (int k0 = 0; k0 < K; k0 += 32) {
    stage128x32(Ahi, m0, K, k0, lds,         tid);
    stage128x32(Alo, m0, K, k0, lds + 4096,  tid);
    stage128x32(Bhi, n0, K, k0, lds + 8192,  tid);
    stage128x32(Blo, n0, K, k0, lds + 12288, tid);
    __syncthreads();

    bf16x8 ah[2][2], al[2][2], bh[2][2], bl[2][2];
    #pragma unroll
    for (int mt = 0; mt < 2; mt++) {
      const int row = wr * 64 + mt * 32 + r5;
      #pragma unroll
      for (int t = 0; t < 2; t++) {
        const int off = row * 32 + (((t * 32 + g * 16) ^ ((row & 3) << 4)) >> 1);
        ah[mt][t] = *reinterpret_cast<const bf16x8*>(&lds[off]);
        al[mt][t] = *reinterpret_cast<const bf16x8*>(&lds[4096 + off]);
      }
    }
    #pragma unroll
    for (int nt = 0; nt < 2; nt++) {
      const int col = wc * 64 + nt * 32 + r5;
      #pragma unroll
      for (int t = 0; t < 2; t++) {
        const int off = col * 32 + (((t * 32 + g * 16) ^ ((col & 3) << 4)) >> 1);
        bh[nt][t] = *reinterpret_cast<const bf16x8*>(&lds[8192 + off]);
        bl[nt][t] = *reinterpret_cast<const bf16x8*>(&lds[12288 + off]);
      }
    }
    #pragma unroll
    for (int mt = 0; mt < 2; mt++)
      #pragma unroll
      for (int nt = 0; nt < 2; nt++)
        #pragma unroll
        for (int t = 0; t < 2; t++) {
          acc[mt][nt] = __builtin_amdgcn_mfma_f32_32x32x16_bf16(ah[mt][t], bh[nt][t], acc[mt][nt], 0, 0, 0);
          acc[mt][nt] = __builtin_amdgcn_mfma_f32_32x32x16_bf16(ah[mt][t], bl[nt][t], acc[mt][nt], 0, 0, 0);
          acc[mt][nt] = __builtin_amdgcn_mfma_f32_32x32x16_bf16(al[mt][t], bh[nt][t], acc[mt][nt], 0, 0, 0);
        }
    __syncthreads();
  }

  // epilogue; 32x32 C layout: col = lane&31, row = (r&3) + 8*(r>>2) + 4*(lane>>5)
  #pragma unroll
  for (int nt = 0; nt < 2; nt++) {
    const int gcol = n0 + wc * 64 + nt * 32 + r5;
    const float bv = bias[gcol];
    #pragma unroll
    for (int mt = 0; mt < 2; mt++) {
      #pragma unroll
      for (int r = 0; r < 16; r++) {
        const int grow = m0 + wr * 64 + mt * 32 + (r & 3) + ((r >> 2) << 3) + (g << 2);
        float v = acc[mt][nt][r] + bv;
        if constexpr (EPI == EPI_RESID) {
          const size_t o = (size_t)grow * N + gcol;
          outf[o] = v + resid[o];
        } else if constexpr (EPI == EPI_RELU) {
          v = fmaxf(v, 0.0f);
          const size_t o = (size_t)grow * N + gcol;
          const u16 h = f2bf(v);
          ohi[o] = h; olo[o] = f2bf(v - bf2f(h));
        } else {
          const int b = grow >> 11, s = grow & 2047;
          const int hh = gcol >> 6, d = gcol & 63;
          size_t o;
          if constexpr (EPI == EPI_QK)
            o = ((size_t)(b * HEADS + hh) * SEQ + s) * DEPTH + d;   // [BH][S][64]
          else
            o = ((size_t)(b * HEADS + hh) * DEPTH + d) * SEQ + s;   // V^T: [BH][64][S]
          const u16 h = f2bf(v);
          ohi[o] = h; olo[o] = f2bf(v - bf2f(h));
        }
      }
    }
  }
}

// ---------------- flash attention, bf16x2-split QK^T and PV ----------------
// R2: K/V tiles (64 kv x 64, hi+lo; V stored transposed [D][S]) staged into LDS
// shared by the block's 4 waves, double-buffered, counted vmcnt(8), raw barriers.
// Tiles XOR-16B-swizzled (linear gload_lds dest + pre-swizzled source, rule 21);
// b128 fragment reads then hit the 8-cy wave64 floor (8 lanes per 4-bank group).
__device__ __forceinline__ void stage_tile64(const u16* __restrict__ src, int gstride,
                                             u16* ldsbase, int tid) {
  #pragma unroll
  for (int i = 0; i < 2; i++) {
    const int c = i * 256 + tid;              // 16B-chunk id 0..511 (tile = 8KB)
    const int r = c >> 3;                      // tile row 0..63 (row = 128B)
    const int q = (c & 7) ^ (r & 7);           // inverse swizzle on source
    gload_lds16(src + (size_t)r * gstride + q * 8,
                ldsbase + ((i * 256 + (tid & 192)) << 3));   // wave-uniform dest
  }
}

__global__ __launch_bounds__(256, 2)
void k_attn(const u16* __restrict__ qh, const u16* __restrict__ ql,
            const u16* __restrict__ kh, const u16* __restrict__ kl,
            const u16* __restrict__ vh, const u16* __restrict__ vl,
            u16* __restrict__ ch, u16* __restrict__ cl) {
  // 2 buffers x [Khi|Klo|Vhi|Vlo] (4096 u16 each) + 4 waves x 2048 u16 P = 80KB
  __shared__ u16 lds[2 * 16384 + 8192];
  const int tid = threadIdx.x, lane = tid & 63, w = tid >> 6;
  const int l15 = lane & 15, g = lane >> 4;
  const int bh = blockIdx.y;
  const int b = bh >> 4, hd = bh & 15;
  const int q0 = blockIdx.x * 64 + w * 16;
  u16* myp = lds + 2 * 16384 + w * 2048;

  const size_t khead = (size_t)bh * (SEQ * DEPTH);   // K: [BH][S][64]
  const size_t vhead = (size_t)bh * (DEPTH * SEQ);   // V^T: [BH][64][S]

  bf16x8 qfh[2], qfl[2];
  #pragma unroll
  for (int t = 0; t < 2; t++) {
    const size_t qi = ((size_t)bh * SEQ + q0 + l15) * DEPTH + t * 32 + g * 8;
    qfh[t] = *reinterpret_cast<const bf16x8*>(&qh[qi]);
    qfl[t] = *reinterpret_cast<const bf16x8*>(&ql[qi]);
  }

  f32x4 o[4];
  #pragma unroll
  for (int dt = 0; dt < 4; dt++)
    #pragma unroll
    for (int e = 0; e < 4; e++) o[dt][e] = 0.f;
  float m_run[4] = {-1e30f, -1e30f, -1e30f, -1e30f};
  float l_run[4] = {0.f, 0.f, 0.f, 0.f};

  // prologue: stage tile 0 into buffer 0 (8 gload_lds per wave)
  stage_tile64(kh + khead, DEPTH, lds,         tid);
  stage_tile64(kl + khead, DEPTH, lds + 4096,  tid);
  stage_tile64(vh + vhead, SEQ,   lds + 8192,  tid);
  stage_tile64(vl + vhead, SEQ,   lds + 12288, tid);

  const int NT = SEQ / 64;
  for (int it = 0; it < NT; ++it) {
    const int cur = it & 1;
    // issue next tile's stage into the other buffer (safe: end-of-prev-iter
    // barrier guarantees every wave finished reading it)
    if (it + 1 < NT) {
      u16* Bn = lds + (cur ^ 1) * 16384;
      const size_t ko = khead + (size_t)(it + 1) * 64 * DEPTH;
      const size_t vo = vhead + (size_t)(it + 1) * 64;
      stage_tile64(kh + ko, DEPTH, Bn,         tid);
      stage_tile64(kl + ko, DEPTH, Bn + 4096,  tid);
      stage_tile64(vh + vo, SEQ,   Bn + 8192,  tid);
      stage_tile64(vl + vo, SEQ,   Bn + 12288, tid);
      asm volatile("s_waitcnt vmcnt(8)" ::: "memory");   // current tile's 8 done
    } else {
      asm volatile("s_waitcnt vmcnt(0)" ::: "memory");
    }
    __builtin_amdgcn_s_barrier();
    __builtin_amdgcn_sched_barrier(0);

    const u16* Kh = lds + cur * 16384;
    const u16* Kl = Kh + 4096;
    const u16* Vh = Kh + 8192;
    const u16* Vl = Kh + 12288;

    // QK^T: S[q=16][kv=64], B-operand = K rows from swizzled LDS
    f32x4 s[4];
    #pragma unroll
    for (int ct = 0; ct < 4; ct++) {
      f32x4 sa;
      #pragma unroll
      for (int e = 0; e < 4; e++) sa[e] = 0.f;
      const int row = ct * 16 + l15;
      #pragma unroll
      for (int t = 0; t < 2; t++) {
        const int idx = row * 64 + ((t * 32 + g * 8) ^ ((row & 7) << 3));
        const bf16x8 kfh = *reinterpret_cast<const bf16x8*>(&Kh[idx]);
        const bf16x8 kfl = *reinterpret_cast<const bf16x8*>(&Kl[idx]);
        sa = __builtin_amdgcn_mfma_f32_16x16x32_bf16(qfh[t], kfh, sa, 0, 0, 0);
        sa = __builtin_amdgcn_mfma_f32_16x16x32_bf16(qfh[t], kfl, sa, 0, 0, 0);
        sa = __builtin_amdgcn_mfma_f32_16x16x32_bf16(qfl[t], kfh, sa, 0, 0, 0);
      }
      s[ct] = sa;
    }

    // online softmax; C layout row = g*4+j, col = ct*16+l15
    float p[4][4];
    #pragma unroll
    for (int j = 0; j < 4; j++) {
      float mx = fmaxf(fmaxf(s[0][j], s[1][j]), fmaxf(s[2][j], s[3][j])) * 0.125f;
      #pragma unroll
      for (int m = 1; m < 16; m <<= 1) mx = fmaxf(mx, __shfl_xor(mx, m));
      const float mn = fmaxf(m_run[j], mx);
      const float alpha = __expf(m_run[j] - mn);
      m_run[j] = mn;
      float ls = 0.f;
      #pragma unroll
      for (int ct = 0; ct < 4; ct++) {
        const float pv = __expf(s[ct][j] * 0.125f - mn);
        p[ct][j] = pv; ls += pv;
      }
      #pragma unroll
      for (int m = 1; m < 16; m <<= 1) ls += __shfl_xor(ls, m);
      l_run[j] = l_run[j] * alpha + ls;
      #pragma unroll
      for (int dt = 0; dt < 4; dt++) o[dt][j] *= alpha;
    }

    // P -> wave-private swizzled LDS (C-layout -> A-fragment layout)
    #pragma unroll
    for (int ct = 0; ct < 4; ct++)
      #pragma unroll
      for (int j = 0; j < 4; j++) {
        const int R = g * 4 + j;
        const int c = ct * 16 + l15;
        const int e = R * 64 + (c ^ ((R & 7) << 3));
        const float pv = p[ct][j];
        const u16 h = f2bf(pv);
        myp[e] = h;
        myp[1024 + e] = f2bf(pv - bf2f(h));
      }
    asm volatile("s_waitcnt lgkmcnt(0)" ::: "memory");

    bf16x8 pah[2], pal[2];
    #pragma unroll
    for (int t = 0; t < 2; t++) {
      const int e = l15 * 64 + ((t * 32 + g * 8) ^ ((l15 & 7) << 3));
      pah[t] = *reinterpret_cast<const bf16x8*>(&myp[e]);
      pal[t] = *reinterpret_cast<const bf16x8*>(&myp[1024 + e]);
    }

    // PV: B-operand = V^T rows (d) from swizzled LDS
    #pragma unroll
    for (int dt = 0; dt < 4; dt++) {
      const int row = dt * 16 + l15;
      #pragma unroll
      for (int t = 0; t < 2; t++) {
        const int idx = row * 64 + ((t * 32 + g * 8) ^ ((row & 7) << 3));
        const bf16x8 vfh = *reinterpret_cast<const bf16x8*>(&Vh[idx]);
        const bf16x8 vfl = *reinterpret_cast<const bf16x8*>(&Vl[idx]);
        o[dt] = __builtin_amdgcn_mfma_f32_16x16x32_bf16(pah[t], vfh, o[dt], 0, 0, 0);
        o[dt] = __builtin_amdgcn_mfma_f32_16x16x32_bf16(pah[t], vfl, o[dt], 0, 0, 0);
        o[dt] = __builtin_amdgcn_mfma_f32_16x16x32_bf16(pal[t], vfh, o[dt], 0, 0, 0);
      }
    }
    __builtin_amdgcn_s_barrier();   // all reads of buffer `cur` done before next stage
  }

  #pragma unroll
  for (int j = 0; j < 4; j++) {
    const float inv = 1.0f / l_run[j];
    const int srow = q0 + g * 4 + j;
    #pragma unroll
    for (int dt = 0; dt < 4; dt++) {
      const float v = o[dt][j] * inv;
      const size_t oo = ((size_t)(b * SEQ + srow)) * DM + hd * 64 + dt * 16 + l15;
      const u16 h = f2bf(v);
      ch[oo] = h; cl[oo] = f2bf(v - bf2f(h));
    }
  }
}

// ---------------- LayerNorm (one row per block), optional split output ----------------
template <bool SPLIT>
__global__ __launch_bounds__(256)
void k_ln(const float* __restrict__ x, const float* __restrict__ gam,
          const float* __restrict__ bet, float* __restrict__ outf,
          u16* __restrict__ ohi, u16* __restrict__ olo) {
  const int row = blockIdx.x, tid = threadIdx.x, lane = tid & 63, w = tid >> 6;
  __shared__ float r1[4], r2[4];
  const float4 v = reinterpret_cast<const float4*>(x + (size_t)row * DM)[tid];
  float s = v.x + v.y + v.z + v.w;
  #pragma unroll
  for (int m = 1; m < 64; m <<= 1) s += __shfl_xor(s, m);
  if (lane == 0) r1[w] = s;
  __syncthreads();
  const float mu = (r1[0] + r1[1] + r1[2] + r1[3]) * (1.0f / DM);
  float4 c; c.x = v.x - mu; c.y = v.y - mu; c.z = v.z - mu; c.w = v.w - mu;
  float q = c.x * c.x + c.y * c.y + c.z * c.z + c.w * c.w;
  #pragma unroll
  for (int m = 1; m < 64; m <<= 1) q += __shfl_xor(q, m);
  if (lane == 0) r2[w] = q;
  __syncthreads();
  const float var = (r2[0] + r2[1] + r2[2] + r2[3]) * (1.0f / DM);
  const float rs = rsqrtf(var + 1e-6f);
  const float4 g4 = reinterpret_cast<const float4*>(gam)[tid];
  const float4 b4 = reinterpret_cast<const float4*>(bet)[tid];
  float4 o;
  o.x = c.x * rs * g4.x + b4.x;
  o.y = c.y * rs * g4.y + b4.y;
  o.z = c.z * rs * g4.z + b4.z;
  o.w = c.w * rs * g4.w + b4.w;
  reinterpret_cast<float4*>(outf + (size_t)row * DM)[tid] = o;
  if constexpr (SPLIT) {
    ushort4 h, l;
    h.x = f2bf(o.x); l.x = f2bf(o.x - bf2f(h.x));
    h.y = f2bf(o.y); l.y = f2bf(o.y - bf2f(h.y));
    h.z = f2bf(o.z); l.z = f2bf(o.z - bf2f(h.z));
    h.w = f2bf(o.w); l.w = f2bf(o.w - bf2f(h.w));
    reinterpret_cast<ushort4*>(ohi + (size_t)row * DM)[tid] = h;
    reinterpret_cast<ushort4*>(olo + (size_t)row * DM)[tid] = l;
  }
}

extern "C" void kernel_launch(void* const* d_in, const int* in_sizes, int n_in,
                              void* d_out, int out_size, void* d_ws, size_t ws_size,
                              hipStream_t stream) {
  const float* x   = (const float*)d_in[0];
  const float* wq  = (const float*)d_in[1];
  const float* bq  = (const float*)d_in[2];
  const float* wk  = (const float*)d_in[3];
  const float* bk  = (const float*)d_in[4];
  const float* wv  = (const float*)d_in[5];
  const float* bv  = (const float*)d_in[6];
  const float* wo  = (const float*)d_in[7];
  const float* bo  = (const float*)d_in[8];
  const float* w1  = (const float*)d_in[9];
  const float* b1  = (const float*)d_in[10];
  const float* w2  = (const float*)d_in[11];
  const float* b2  = (const float*)d_in[12];
  const float* g1  = (const float*)d_in[13];
  const float* be1 = (const float*)d_in[14];
  const float* g2  = (const float*)d_in[15];
  const float* be2 = (const float*)d_in[16];
  float* out = (float*)d_out;
  char* ws = (char*)d_ws;
  const size_t MB = (size_t)1 << 20;
  if (ws_size < 160 * MB) return;

  u16* wqt_h = (u16*)(ws + 0 * MB);   u16* wqt_l = (u16*)(ws + 2 * MB);
  u16* wkt_h = (u16*)(ws + 4 * MB);   u16* wkt_l = (u16*)(ws + 6 * MB);
  u16* wvt_h = (u16*)(ws + 8 * MB);   u16* wvt_l = (u16*)(ws + 10 * MB);
  u16* wot_h = (u16*)(ws + 12 * MB);  u16* wot_l = (u16*)(ws + 14 * MB);
  u16* w1t_h = (u16*)(ws + 16 * MB);  u16* w1t_l = (u16*)(ws + 24 * MB);
  u16* w2t_h = (u16*)(ws + 32 * MB);  u16* w2t_l = (u16*)(ws + 40 * MB);
  u16* xh  = (u16*)(ws + 48 * MB);    u16* xl  = (u16*)(ws + 56 * MB);
  u16* qh_ = (u16*)(ws + 64 * MB);    u16* ql_ = (u16*)(ws + 72 * MB);
  u16* kh_ = (u16*)(ws + 80 * MB);    u16* kl_ = (u16*)(ws + 88 * MB);
  u16* vh_ = (u16*)(ws + 96 * MB);    u16* vl_ = (u16*)(ws + 104 * MB);
  u16* hh_ = (u16*)(ws + 48 * MB);    u16* hl_ = (u16*)(ws + 80 * MB);
  u16* cth = (u16*)(ws + 112 * MB);   u16* ctl = (u16*)(ws + 120 * MB);
  u16* o1h = (u16*)(ws + 112 * MB);   u16* o1l = (u16*)(ws + 120 * MB);
  float* y   = (float*)(ws + 128 * MB);
  float* o1f = (float*)(ws + 144 * MB);

  k_split<<<4096, 256, 0, stream>>>(x, xh, xl, MROWS * DM / 4);
  k_tsplit<<<dim3(32, 32),  256, 0, stream>>>(wq, wqt_h, wqt_l, DM, DM);
  k_tsplit<<<dim3(32, 32),  256, 0, stream>>>(wk, wkt_h, wkt_l, DM, DM);
  k_tsplit<<<dim3(32, 32),  256, 0, stream>>>(wv, wvt_h, wvt_l, DM, DM);
  k_tsplit<<<dim3(32, 32),  256, 0, stream>>>(wo, wot_h, wot_l, DM, DM);
  k_tsplit<<<dim3(128, 32), 256, 0, stream>>>(w1, w1t_h, w1t_l, DM, DFF);
  k_tsplit<<<dim3(32, 128), 256, 0, stream>>>(w2, w2t_h, w2t_l, DFF, DM);

  k_gemm<EPI_QK><<<dim3(8, 32), 256, 0, stream>>>(xh, xl, wqt_h, wqt_l, bq, MROWS, DM, DM, nullptr, nullptr, qh_, ql_);
  k_gemm<EPI_QK><<<dim3(8, 32), 256, 0, stream>>>(xh, xl, wkt_h, wkt_l, bk, MROWS, DM, DM, nullptr, nullptr, kh_, kl_);
  k_gemm<EPI_VT><<<dim3(8, 32), 256, 0, stream>>>(xh, xl, wvt_h, wvt_l, bv, MROWS, DM, DM, nullptr, nullptr, vh_, vl_);

  k_attn<<<dim3(32, 32), 256, 0, stream>>>(qh_, ql_, kh_, kl_, vh_, vl_, cth, ctl);

  k_gemm<EPI_RESID><<<dim3(8, 32), 256, 0, stream>>>(cth, ctl, wot_h, wot_l, bo, MROWS, DM, DM, y, x, nullptr, nullptr);
  k_ln<true><<<MROWS, 256, 0, stream>>>(y, g1, be1, o1f, o1h, o1l);

  k_gemm<EPI_RELU><<<dim3(32, 32), 256, 0, stream>>>(o1h, o1l, w1t_h, w1t_l, b1, MROWS, DFF, DM, nullptr, nullptr, hh_, hl_);
  k_gemm<EPI_RESID><<<dim3(8, 32), 256, 0, stream>>>(hh_, hl_, w2t_h, w2t_l, b2, MROWS, DM, DFF, y, o1f, nullptr, nullptr);
  k_ln<false><<<MROWS, 256, 0, stream>>>(y, g2, be2, out, nullptr, nullptr);
}

// Round 3
// 712.448 us; speedup vs baseline: 1.6405x; 1.2636x over previous
//
#include <hip/hip_runtime.h>
#include <stdint.h>

// Transformer block, fp32 in/out, internally bf16x2-split MFMA (hi+lo, 3 products).
// R3: k_gemm — double-buffered counted-vmcnt staging (T4), corrected LDS swizzle
// ((row>>1)&3 — the (row&3) version was a measured 2-way b128 conflict, 2.5e7 cy),
// XCD-chunked block swizzle + 4x4 supertiles for L2 locality (T1).

#define DM    1024
#define SEQ   2048
#define HEADS 16
#define DEPTH 64
#define DFF   4096
#define MROWS 4096   // B*S

typedef __bf16 bf16x8 __attribute__((ext_vector_type(8)));
typedef float  f32x4  __attribute__((ext_vector_type(4)));
typedef float  f32x16 __attribute__((ext_vector_type(16)));
typedef unsigned short u16;

__device__ __forceinline__ u16 f2bf(float f) {
  uint32_t u = __float_as_uint(f);
  u += 0x7fffu + ((u >> 16) & 1u);        // RNE; inputs are finite
  return (u16)(u >> 16);
}
__device__ __forceinline__ float bf2f(u16 h) {
  return __uint_as_float(((uint32_t)h) << 16);
}

__device__ __forceinline__ void gload_lds16(const u16* g, u16* l) {
  __builtin_amdgcn_global_load_lds(
      (const __attribute__((address_space(1))) uint32_t*)g,
      (__attribute__((address_space(3))) uint32_t*)l, 16, 0, 0);
}

// ---------------- split fp32 -> bf16 hi/lo ----------------
__global__ void k_split(const float* __restrict__ x, u16* __restrict__ hi,
                        u16* __restrict__ lo, int n4) {
  int i = blockIdx.x * 256 + threadIdx.x;
  if (i >= n4) return;
  float4 v = reinterpret_cast<const float4*>(x)[i];
  ushort4 h, l;
  h.x = f2bf(v.x); l.x = f2bf(v.x - bf2f(h.x));
  h.y = f2bf(v.y); l.y = f2bf(v.y - bf2f(h.y));
  h.z = f2bf(v.z); l.z = f2bf(v.z - bf2f(h.z));
  h.w = f2bf(v.w); l.w = f2bf(v.w - bf2f(h.w));
  reinterpret_cast<ushort4*>(hi)[i] = h;
  reinterpret_cast<ushort4*>(lo)[i] = l;
}

// ---------------- transpose + split: in[K][N] fp32 -> out[N][K] bf16 hi/lo ----------------
__global__ void k_tsplit(const float* __restrict__ in, u16* __restrict__ oh,
                         u16* __restrict__ ol, int K, int N) {
  __shared__ float t[32][33];
  const int tx = threadIdx.x & 31, ty = threadIdx.x >> 5;
  const int c0 = blockIdx.x * 32, r0 = blockIdx.y * 32;
  #pragma unroll
  for (int i = 0; i < 4; i++)
    t[ty + 8 * i][tx] = in[(size_t)(r0 + ty + 8 * i) * N + c0 + tx];
  __syncthreads();
  #pragma unroll
  for (int i = 0; i < 4; i++) {
    const int n = c0 + ty + 8 * i, k = r0 + tx;
    const float v = t[tx][ty + 8 * i];
    const u16 h = f2bf(v);
    oh[(size_t)n * K + k] = h;
    ol[(size_t)n * K + k] = f2bf(v - bf2f(h));
  }
}

// ---------------- split GEMM: C = A[M,K] @ B^T[N,K] + bias, bf16x2 operands ----------------
// 128x128 tile, BK=32, 4 waves (64x64/wave = 2x2 of mfma_f32_32x32x16_bf16 x 3 products).
// Tiles [128][32] u16, row = 64B = 4 granules; swizzle: stored chunk = logical ^ ((row>>1)&3)
// -> 8 consecutive rows hit 8 distinct 16B granules (conflict-free b128).
enum { EPI_QK = 0, EPI_VT = 1, EPI_RESID = 2, EPI_RELU = 3 };

__device__ __forceinline__ void stage4(const u16* __restrict__ Ahi, const u16* __restrict__ Alo,
                                       const u16* __restrict__ Bhi, const u16* __restrict__ Blo,
                                       int m0, int n0, int K, int k0,
                                       u16* buf, int tid, int w) {
  #pragma unroll
  for (int rnd = 0; rnd < 2; rnd++) {
    const int cid = rnd * 256 + tid;
    const int r = cid >> 2;
    const int lc = (cid & 3) ^ ((r >> 1) & 3);   // inverse swizzle on source (rule 21)
    const size_t asrc = (size_t)(m0 + r) * K + k0 + lc * 8;
    const size_t bsrc = (size_t)(n0 + r) * K + k0 + lc * 8;
    u16* dst = buf + rnd * 2048 + w * 512;       // wave-uniform dest, lanes linear
    gload_lds16(Ahi + asrc, dst);
    gload_lds16(Alo + asrc, dst + 4096);
    gload_lds16(Bhi + bsrc, dst + 8192);
    gload_lds16(Blo + bsrc, dst + 12288);
  }
}

template <int EPI>
__global__ __launch_bounds__(256, 2)
void k_gemm(const u16* __restrict__ Ahi, const u16* __restrict__ Alo,
            const u16* __restrict__ Bhi, const u16* __restrict__ Blo,
            const float* __restrict__ bias, int M, int N, int K,
            float* __restrict__ outf, const float* __restrict__ resid,
            u16* __restrict__ ohi, u16* __restrict__ olo) {
  __shared__ u16 lds[32768];   // 2 x [Ahi|Alo|Bhi|Blo], each 128x32 u16 (64KB total)
  const int tid = threadIdx.x;
  const int lane = tid & 63;
  const int w = tid >> 6, wr = w >> 1, wc = w & 1;
  const int r5 = lane & 31, g = lane >> 5;

  // XCD-chunked swizzle (grids %8==0) + 4x4 supertiles (~4MB working set / XCD L2)
  const int nwg = gridDim.x;
  const int cpx = nwg >> 3;
  const int bid = blockIdx.x;
  const int lid = (bid & 7) * cpx + (bid >> 3);
  const int GN = N >> 7;
  const int stpr = GN >> 2;
  const int st = lid >> 4, wi = lid & 15;
  const int mb = (st / stpr) * 4 + (wi >> 2);
  const int nb = (st % stpr) * 4 + (wi & 3);
  const int m0 = mb * 128, n0 = nb * 128;

  f32x16 acc[2][2];
  #pragma unroll
  for (int a = 0; a < 2; a++)
    #pragma unroll
    for (int b = 0; b < 2; b++)
      #pragma unroll
      for (int e = 0; e < 16; e++) acc[a][b][e] = 0.f;

  const int NT = K >> 5;
  // prologue: tile 0 -> buffer 0
  stage4(Ahi, Alo, Bhi, Blo, m0, n0, K, 0, lds, tid, w);

  for (int it = 0; it < NT; ++it) {
    const int cur = it & 1;
    u16* bufc = lds + cur * 16384;
    if (it + 1 < NT) {
      stage4(Ahi, Alo, Bhi, Blo, m0, n0, K, (it + 1) << 5, lds + (cur ^ 1) * 16384, tid, w);
      asm volatile("s_waitcnt vmcnt(8)" ::: "memory");   // current tile's 8 loads done
    } else {
      asm volatile("s_waitcnt vmcnt(0)" ::: "memory");
    }
    __builtin_amdgcn_s_barrier();
    __builtin_amdgcn_sched_barrier(0);

    bf16x8 ah[2][2], al[2][2], bh[2][2], bl[2][2];
    #pragma unroll
    for (int mt = 0; mt < 2; mt++) {
      const int row = wr * 64 + mt * 32 + r5;
      #pragma unroll
      for (int t = 0; t < 2; t++) {
        const int off = row * 32 + (((t * 2 + g) ^ ((row >> 1) & 3)) << 3);
        ah[mt][t] = *reinterpret_cast<const bf16x8*>(&bufc[off]);
        al[mt][t] = *reinterpret_cast<const bf16x8*>(&bufc[4096 + off]);
      }
    }
    #pragma unroll
    for (int nt = 0; nt < 2; nt++) {
      const int col = wc * 64 + nt * 32 + r5;
      #pragma unroll
      for (int t = 0; t < 2; t++) {
        const int off = col * 32 + (((t * 2 + g) ^ ((col >> 1) & 3)) << 3);
        bh[nt][t] = *reinterpret_cast<const bf16x8*>(&bufc[8192 + off]);
        bl[nt][t] = *reinterpret_cast<const bf16x8*>(&bufc[12288 + off]);
      }
    }
    #pragma unroll
    for (int mt = 0; mt < 2; mt++)
      #pragma unroll
      for (int nt = 0; nt < 2; nt++)
        #pragma unroll
        for (int t = 0; t < 2; t++) {
          acc[mt][nt] = __builtin_amdgcn_mfma_f32_32x32x16_bf16(ah[mt][t], bh[nt][t], acc[mt][nt], 0, 0, 0);
          acc[mt][nt] = __builtin_amdgcn_mfma_f32_32x32x16_bf16(ah[mt][t], bl[nt][t], acc[mt][nt], 0, 0, 0);
          acc[mt][nt] = __builtin_amdgcn_mfma_f32_32x32x16_bf16(al[mt][t], bh[nt][t], acc[mt][nt], 0, 0, 0);
        }
    __builtin_amdgcn_s_barrier();   // all reads of buffer `cur` done before it+1 stages into it
  }

  // epilogue; 32x32 C layout: col = lane&31, row = (r&3) + 8*(r>>2) + 4*(lane>>5)
  #pragma unroll
  for (int nt = 0; nt < 2; nt++) {
    const int gcol = n0 + wc * 64 + nt * 32 + r5;
    const float bv = bias[gcol];
    #pragma unroll
    for (int mt = 0; mt < 2; mt++) {
      #pragma unroll
      for (int r = 0; r < 16; r++) {
        const int grow = m0 + wr * 64 + mt * 32 + (r & 3) + ((r >> 2) << 3) + (g << 2);
        float v = acc[mt][nt][r] + bv;
        if constexpr (EPI == EPI_RESID) {
          const size_t o = (size_t)grow * N + gcol;
          outf[o] = v + resid[o];
        } else if constexpr (EPI == EPI_RELU) {
          v = fmaxf(v, 0.0f);
          const size_t o = (size_t)grow * N + gcol;
          const u16 h = f2bf(v);
          ohi[o] = h; olo[o] = f2bf(v - bf2f(h));
        } else {
          const int b = grow >> 11, s = grow & 2047;
          const int hh = gcol >> 6, d = gcol & 63;
          size_t o;
          if constexpr (EPI == EPI_QK)
            o = ((size_t)(b * HEADS + hh) * SEQ + s) * DEPTH + d;   // [BH][S][64]
          else
            o = ((size_t)(b * HEADS + hh) * DEPTH + d) * SEQ + s;   // V^T: [BH][64][S]
          const u16 h = f2bf(v);
          ohi[o] = h; olo[o] = f2bf(v - bf2f(h));
        }
      }
    }
  }
}

// ---------------- flash attention, bf16x2-split QK^T and PV (unchanged from R2) ----------------
__device__ __forceinline__ void stage_tile64(const u16* __restrict__ src, int gstride,
                                             u16* ldsbase, int tid) {
  #pragma unroll
  for (int i = 0; i < 2; i++) {
    const int c = i * 256 + tid;
    const int r = c >> 3;
    const int q = (c & 7) ^ (r & 7);
    gload_lds16(src + (size_t)r * gstride + q * 8,
                ldsbase + ((i * 256 + (tid & 192)) << 3));
  }
}

__global__ __launch_bounds__(256, 2)
void k_attn(const u16* __restrict__ qh, const u16* __restrict__ ql,
            const u16* __restrict__ kh, const u16* __restrict__ kl,
            const u16* __restrict__ vh, const u16* __restrict__ vl,
            u16* __restrict__ ch, u16* __restrict__ cl) {
  __shared__ u16 lds[2 * 16384 + 8192];
  const int tid = threadIdx.x, lane = tid & 63, w = tid >> 6;
  const int l15 = lane & 15, g = lane >> 4;
  const int bh = blockIdx.y;
  const int b = bh >> 4, hd = bh & 15;
  const int q0 = blockIdx.x * 64 + w * 16;
  u16* myp = lds + 2 * 16384 + w * 2048;

  const size_t khead = (size_t)bh * (SEQ * DEPTH);
  const size_t vhead = (size_t)bh * (DEPTH * SEQ);

  bf16x8 qfh[2], qfl[2];
  #pragma unroll
  for (int t = 0; t < 2; t++) {
    const size_t qi = ((size_t)bh * SEQ + q0 + l15) * DEPTH + t * 32 + g * 8;
    qfh[t] = *reinterpret_cast<const bf16x8*>(&qh[qi]);
    qfl[t] = *reinterpret_cast<const bf16x8*>(&ql[qi]);
  }

  f32x4 o[4];
  #pragma unroll
  for (int dt = 0; dt < 4; dt++)
    #pragma unroll
    for (int e = 0; e < 4; e++) o[dt][e] = 0.f;
  float m_run[4] = {-1e30f, -1e30f, -1e30f, -1e30f};
  float l_run[4] = {0.f, 0.f, 0.f, 0.f};

  stage_tile64(kh + khead, DEPTH, lds,         tid);
  stage_tile64(kl + khead, DEPTH, lds + 4096,  tid);
  stage_tile64(vh + vhead, SEQ,   lds + 8192,  tid);
  stage_tile64(vl + vhead, SEQ,   lds + 12288, tid);

  const int NT = SEQ / 64;
  for (int it = 0; it < NT; ++it) {
    const int cur = it & 1;
    if (it + 1 < NT) {
      u16* Bn = lds + (cur ^ 1) * 16384;
      const size_t ko = khead + (size_t)(it + 1) * 64 * DEPTH;
      const size_t vo = vhead + (size_t)(it + 1) * 64;
      stage_tile64(kh + ko, DEPTH, Bn,         tid);
      stage_tile64(kl + ko, DEPTH, Bn + 4096,  tid);
      stage_tile64(vh + vo, SEQ,   Bn + 8192,  tid);
      stage_tile64(vl + vo, SEQ,   Bn + 12288, tid);
      asm volatile("s_waitcnt vmcnt(8)" ::: "memory");
    } else {
      asm volatile("s_waitcnt vmcnt(0)" ::: "memory");
    }
    __builtin_amdgcn_s_barrier();
    __builtin_amdgcn_sched_barrier(0);

    const u16* Kh = lds + cur * 16384;
    const u16* Kl = Kh + 4096;
    const u16* Vh = Kh + 8192;
    const u16* Vl = Kh + 12288;

    f32x4 s[4];
    #pragma unroll
    for (int ct = 0; ct < 4; ct++) {
      f32x4 sa;
      #pragma unroll
      for (int e = 0; e < 4; e++) sa[e] = 0.f;
      const int row = ct * 16 + l15;
      #pragma unroll
      for (int t = 0; t < 2; t++) {
        const int idx = row * 64 + ((t * 32 + g * 8) ^ ((row & 7) << 3));
        const bf16x8 kfh = *reinterpret_cast<const bf16x8*>(&Kh[idx]);
        const bf16x8 kfl = *reinterpret_cast<const bf16x8*>(&Kl[idx]);
        sa = __builtin_amdgcn_mfma_f32_16x16x32_bf16(qfh[t], kfh, sa, 0, 0, 0);
        sa = __builtin_amdgcn_mfma_f32_16x16x32_bf16(qfh[t], kfl, sa, 0, 0, 0);
        sa = __builtin_amdgcn_mfma_f32_16x16x32_bf16(qfl[t], kfh, sa, 0, 0, 0);
      }
      s[ct] = sa;
    }

    float p[4][4];
    #pragma unroll
    for (int j = 0; j < 4; j++) {
      float mx = fmaxf(fmaxf(s[0][j], s[1][j]), fmaxf(s[2][j], s[3][j])) * 0.125f;
      #pragma unroll
      for (int m = 1; m < 16; m <<= 1) mx = fmaxf(mx, __shfl_xor(mx, m));
      const float mn = fmaxf(m_run[j], mx);
      const float alpha = __expf(m_run[j] - mn);
      m_run[j] = mn;
      float ls = 0.f;
      #pragma unroll
      for (int ct = 0; ct < 4; ct++) {
        const float pv = __expf(s[ct][j] * 0.125f - mn);
        p[ct][j] = pv; ls += pv;
      }
      #pragma unroll
      for (int m = 1; m < 16; m <<= 1) ls += __shfl_xor(ls, m);
      l_run[j] = l_run[j] * alpha + ls;
      #pragma unroll
      for (int dt = 0; dt < 4; dt++) o[dt][j] *= alpha;
    }

    #pragma unroll
    for (int ct = 0; ct < 4; ct++)
      #pragma unroll
      for (int j = 0; j < 4; j++) {
        const int R = g * 4 + j;
        const int c = ct * 16 + l15;
        const int e = R * 64 + (c ^ ((R & 7) << 3));
        const float pv = p[ct][j];
        const u16 h = f2bf(pv);
        myp[e] = h;
        myp[1024 + e] = f2bf(pv - bf2f(h));
      }
    asm volatile("s_waitcnt lgkmcnt(0)" ::: "memory");

    bf16x8 pah[2], pal[2];
    #pragma unroll
    for (int t = 0; t < 2; t++) {
      const int e = l15 * 64 + ((t * 32 + g * 8) ^ ((l15 & 7) << 3));
      pah[t] = *reinterpret_cast<const bf16x8*>(&myp[e]);
      pal[t] = *reinterpret_cast<const bf16x8*>(&myp[1024 + e]);
    }

    #pragma unroll
    for (int dt = 0; dt < 4; dt++) {
      const int row = dt * 16 + l15;
      #pragma unroll
      for (int t = 0; t < 2; t++) {
        const int idx = row * 64 + ((t * 32 + g * 8) ^ ((row & 7) << 3));
        const bf16x8 vfh = *reinterpret_cast<const bf16x8*>(&Vh[idx]);
        const bf16x8 vfl = *reinterpret_cast<const bf16x8*>(&Vl[idx]);
        o[dt] = __builtin_amdgcn_mfma_f32_16x16x32_bf16(pah[t], vfh, o[dt], 0, 0, 0);
        o[dt] = __builtin_amdgcn_mfma_f32_16x16x32_bf16(pah[t], vfl, o[dt], 0, 0, 0);
        o[dt] = __builtin_amdgcn_mfma_f32_16x16x32_bf16(pal[t], vfh, o[dt], 0, 0, 0);
      }
    }
    __builtin_amdgcn_s_barrier();
  }

  #pragma unroll
  for (int j = 0; j < 4; j++) {
    const float inv = 1.0f / l_run[j];
    const int srow = q0 + g * 4 + j;
    #pragma unroll
    for (int dt = 0; dt < 4; dt++) {
      const float v = o[dt][j] * inv;
      const size_t oo = ((size_t)(b * SEQ + srow)) * DM + hd * 64 + dt * 16 + l15;
      const u16 h = f2bf(v);
      ch[oo] = h; cl[oo] = f2bf(v - bf2f(h));
    }
  }
}

// ---------------- LayerNorm (one row per block), optional split output ----------------
template <bool SPLIT>
__global__ __launch_bounds__(256)
void k_ln(const float* __restrict__ x, const float* __restrict__ gam,
          const float* __restrict__ bet, float* __restrict__ outf,
          u16* __restrict__ ohi, u16* __restrict__ olo) {
  const int row = blockIdx.x, tid = threadIdx.x, lane = tid & 63, w = tid >> 6;
  __shared__ float r1[4], r2[4];
  const float4 v = reinterpret_cast<const float4*>(x + (size_t)row * DM)[tid];
  float s = v.x + v.y + v.z + v.w;
  #pragma unroll
  for (int m = 1; m < 64; m <<= 1) s += __shfl_xor(s, m);
  if (lane == 0) r1[w] = s;
  __syncthreads();
  const float mu = (r1[0] + r1[1] + r1[2] + r1[3]) * (1.0f / DM);
  float4 c; c.x = v.x - mu; c.y = v.y - mu; c.z = v.z - mu; c.w = v.w - mu;
  float q = c.x * c.x + c.y * c.y + c.z * c.z + c.w * c.w;
  #pragma unroll
  for (int m = 1; m < 64; m <<= 1) q += __shfl_xor(q, m);
  if (lane == 0) r2[w] = q;
  __syncthreads();
  const float var = (r2[0] + r2[1] + r2[2] + r2[3]) * (1.0f / DM);
  const float rs = rsqrtf(var + 1e-6f);
  const float4 g4 = reinterpret_cast<const float4*>(gam)[tid];
  const float4 b4 = reinterpret_cast<const float4*>(bet)[tid];
  float4 o;
  o.x = c.x * rs * g4.x + b4.x;
  o.y = c.y * rs * g4.y + b4.y;
  o.z = c.z * rs * g4.z + b4.z;
  o.w = c.w * rs * g4.w + b4.w;
  reinterpret_cast<float4*>(outf + (size_t)row * DM)[tid] = o;
  if constexpr (SPLIT) {
    ushort4 h, l;
    h.x = f2bf(o.x); l.x = f2bf(o.x - bf2f(h.x));
    h.y = f2bf(o.y); l.y = f2bf(o.y - bf2f(h.y));
    h.z = f2bf(o.z); l.z = f2bf(o.z - bf2f(h.z));
    h.w = f2bf(o.w); l.w = f2bf(o.w - bf2f(h.w));
    reinterpret_cast<ushort4*>(ohi + (size_t)row * DM)[tid] = h;
    reinterpret_cast<ushort4*>(olo + (size_t)row * DM)[tid] = l;
  }
}

extern "C" void kernel_launch(void* const* d_in, const int* in_sizes, int n_in,
                              void* d_out, int out_size, void* d_ws, size_t ws_size,
                              hipStream_t stream) {
  const float* x   = (const float*)d_in[0];
  const float* wq  = (const float*)d_in[1];
  const float* bq  = (const float*)d_in[2];
  const float* wk  = (const float*)d_in[3];
  const float* bk  = (const float*)d_in[4];
  const float* wv  = (const float*)d_in[5];
  const float* bv  = (const float*)d_in[6];
  const float* wo  = (const float*)d_in[7];
  const float* bo  = (const float*)d_in[8];
  const float* w1  = (const float*)d_in[9];
  const float* b1  = (const float*)d_in[10];
  const float* w2  = (const float*)d_in[11];
  const float* b2  = (const float*)d_in[12];
  const float* g1  = (const float*)d_in[13];
  const float* be1 = (const float*)d_in[14];
  const float* g2  = (const float*)d_in[15];
  const float* be2 = (const float*)d_in[16];
  float* out = (float*)d_out;
  char* ws = (char*)d_ws;
  const size_t MB = (size_t)1 << 20;
  if (ws_size < 160 * MB) return;

  u16* wqt_h = (u16*)(ws + 0 * MB);   u16* wqt_l = (u16*)(ws + 2 * MB);
  u16* wkt_h = (u16*)(ws + 4 * MB);   u16* wkt_l = (u16*)(ws + 6 * MB);
  u16* wvt_h = (u16*)(ws + 8 * MB);   u16* wvt_l = (u16*)(ws + 10 * MB);
  u16* wot_h = (u16*)(ws + 12 * MB);  u16* wot_l = (u16*)(ws + 14 * MB);
  u16* w1t_h = (u16*)(ws + 16 * MB);  u16* w1t_l = (u16*)(ws + 24 * MB);
  u16* w2t_h = (u16*)(ws + 32 * MB);  u16* w2t_l = (u16*)(ws + 40 * MB);
  u16* xh  = (u16*)(ws + 48 * MB);    u16* xl  = (u16*)(ws + 56 * MB);
  u16* qh_ = (u16*)(ws + 64 * MB);    u16* ql_ = (u16*)(ws + 72 * MB);
  u16* kh_ = (u16*)(ws + 80 * MB);    u16* kl_ = (u16*)(ws + 88 * MB);
  u16* vh_ = (u16*)(ws + 96 * MB);    u16* vl_ = (u16*)(ws + 104 * MB);
  u16* hh_ = (u16*)(ws + 48 * MB);    u16* hl_ = (u16*)(ws + 80 * MB);
  u16* cth = (u16*)(ws + 112 * MB);   u16* ctl = (u16*)(ws + 120 * MB);
  u16* o1h = (u16*)(ws + 112 * MB);   u16* o1l = (u16*)(ws + 120 * MB);
  float* y   = (float*)(ws + 128 * MB);
  float* o1f = (float*)(ws + 144 * MB);

  k_split<<<4096, 256, 0, stream>>>(x, xh, xl, MROWS * DM / 4);
  k_tsplit<<<dim3(32, 32),  256, 0, stream>>>(wq, wqt_h, wqt_l, DM, DM);
  k_tsplit<<<dim3(32, 32),  256, 0, stream>>>(wk, wkt_h, wkt_l, DM, DM);
  k_tsplit<<<dim3(32, 32),  256, 0, stream>>>(wv, wvt_h, wvt_l, DM, DM);
  k_tsplit<<<dim3(32, 32),  256, 0, stream>>>(wo, wot_h, wot_l, DM, DM);
  k_tsplit<<<dim3(128, 32), 256, 0, stream>>>(w1, w1t_h, w1t_l, DM, DFF);
  k_tsplit<<<dim3(32, 128), 256, 0, stream>>>(w2, w2t_h, w2t_l, DFF, DM);

  // 1D grids (M/128)*(N/128), XCD swizzle + supertiling done in-kernel
  k_gemm<EPI_QK><<<256, 256, 0, stream>>>(xh, xl, wqt_h, wqt_l, bq, MROWS, DM, DM, nullptr, nullptr, qh_, ql_);
  k_gemm<EPI_QK><<<256, 256, 0, stream>>>(xh, xl, wkt_h, wkt_l, bk, MROWS, DM, DM, nullptr, nullptr, kh_, kl_);
  k_gemm<EPI_VT><<<256, 256, 0, stream>>>(xh, xl, wvt_h, wvt_l, bv, MROWS, DM, DM, nullptr, nullptr, vh_, vl_);

  k_attn<<<dim3(32, 32), 256, 0, stream>>>(qh_, ql_, kh_, kl_, vh_, vl_, cth, ctl);

  k_gemm<EPI_RESID><<<256, 256, 0, stream>>>(cth, ctl, wot_h, wot_l, bo, MROWS, DM, DM, y, x, nullptr, nullptr);
  k_ln<true><<<MROWS, 256, 0, stream>>>(y, g1, be1, o1f, o1h, o1l);

  k_gemm<EPI_RELU><<<1024, 256, 0, stream>>>(o1h, o1l, w1t_h, w1t_l, b1, MROWS, DFF, DM, nullptr, nullptr, hh_, hl_);
  k_gemm<EPI_RESID><<<256, 256, 0, stream>>>(hh_, hl_, w2t_h, w2t_l, b2, MROWS, DM, DFF, y, o1f, nullptr, nullptr);
  k_ln<false><<<MROWS, 256, 0, stream>>>(y, g2, be2, out, nullptr, nullptr);
}

// Round 6
// 641.815 us; speedup vs baseline: 1.8211x; 1.1101x over previous
//
#include <hip/hip_runtime.h>
#include <stdint.h>

// Transformer block, fp32 in/out, internally bf16x2-split MFMA (hi+lo, 3 products).
// R5 (resubmit; R5 bench was an infra timeout): fix R4's ds_read_b64_tr_b16
// addressing — per-lane gather, slot-addressed: byte addr = W*128 + s*8 delivers
// elem j from LDS elem W*64 + s + j*16 (slot s picks the column of the window's
// 4x16 bf16 tile). Lane addr = subtile_base + (l&15)*8B. Rest of R4 kept: packed
// P^T ds_write_b64, DPP row_ror reduces (VALU pipe), native RNE bf16 casts.

#define DM    1024
#define SEQ   2048
#define HEADS 16
#define DEPTH 64
#define DFF   4096
#define MROWS 4096   // B*S

typedef __bf16 bf16x8 __attribute__((ext_vector_type(8)));
typedef float  f32x4  __attribute__((ext_vector_type(4)));
typedef float  f32x16 __attribute__((ext_vector_type(16)));
typedef unsigned short u16;

__device__ __forceinline__ u16 f2bf(float f) {
  __bf16 h = (__bf16)f;          // RNE (LLVM fptrunc->bfloat), matches manual round
  u16 r; __builtin_memcpy(&r, &h, 2); return r;
}
__device__ __forceinline__ float bf2f(u16 h) {
  return __uint_as_float(((uint32_t)h) << 16);
}

__device__ __forceinline__ void gload_lds16(const u16* g, u16* l) {
  __builtin_amdgcn_global_load_lds(
      (const __attribute__((address_space(1))) uint32_t*)g,
      (__attribute__((address_space(3))) uint32_t*)l, 16, 0, 0);
}

// DPP row_ror all-reduce over the lane's 16-lane row (VALU pipe, no DS traffic)
template <int N>
__device__ __forceinline__ float dppror(float x) {
  return __int_as_float(__builtin_amdgcn_update_dpp(
      0, __float_as_int(x), 0x120 | N, 0xF, 0xF, true));
}
__device__ __forceinline__ float rmax16(float v) {
  v = fmaxf(v, dppror<8>(v)); v = fmaxf(v, dppror<4>(v));
  v = fmaxf(v, dppror<2>(v)); v = fmaxf(v, dppror<1>(v));
  return v;
}
__device__ __forceinline__ float rsum16(float v) {
  v += dppror<8>(v); v += dppror<4>(v); v += dppror<2>(v); v += dppror<1>(v);
  return v;
}

// ds_read_b64_tr_b16 (per-lane gather, slot-addressed): byte addr = W*128 + s*8
// -> elem j delivered from LDS elem W*64 + s + j*16. To read column c of a 4x16
// bf16 tile at tile_base: addr = tile_base + c*8 BYTES (not c*2).
__device__ __forceinline__ uint2 tr_b64(const u16* p) {
  uint2 r;
  asm volatile("ds_read_b64_tr_b16 %0, %1"
               : "=v"(r)
               : "v"((const __attribute__((address_space(3))) u16*)p)
               : "memory");
  return r;
}

// ---------------- split fp32 -> bf16 hi/lo ----------------
__global__ void k_split(const float* __restrict__ x, u16* __restrict__ hi,
                        u16* __restrict__ lo, int n4) {
  int i = blockIdx.x * 256 + threadIdx.x;
  if (i >= n4) return;
  float4 v = reinterpret_cast<const float4*>(x)[i];
  ushort4 h, l;
  h.x = f2bf(v.x); l.x = f2bf(v.x - bf2f(h.x));
  h.y = f2bf(v.y); l.y = f2bf(v.y - bf2f(h.y));
  h.z = f2bf(v.z); l.z = f2bf(v.z - bf2f(h.z));
  h.w = f2bf(v.w); l.w = f2bf(v.w - bf2f(h.w));
  reinterpret_cast<ushort4*>(hi)[i] = h;
  reinterpret_cast<ushort4*>(lo)[i] = l;
}

// ---------------- transpose + split: in[K][N] fp32 -> out[N][K] bf16 hi/lo ----------------
__global__ void k_tsplit(const float* __restrict__ in, u16* __restrict__ oh,
                         u16* __restrict__ ol, int K, int N) {
  __shared__ float t[32][33];
  const int tx = threadIdx.x & 31, ty = threadIdx.x >> 5;
  const int c0 = blockIdx.x * 32, r0 = blockIdx.y * 32;
  #pragma unroll
  for (int i = 0; i < 4; i++)
    t[ty + 8 * i][tx] = in[(size_t)(r0 + ty + 8 * i) * N + c0 + tx];
  __syncthreads();
  #pragma unroll
  for (int i = 0; i < 4; i++) {
    const int n = c0 + ty + 8 * i, k = r0 + tx;
    const float v = t[tx][ty + 8 * i];
    const u16 h = f2bf(v);
    oh[(size_t)n * K + k] = h;
    ol[(size_t)n * K + k] = f2bf(v - bf2f(h));
  }
}

// ---------------- split GEMM: C = A[M,K] @ B^T[N,K] + bias, bf16x2 operands ----------------
enum { EPI_QK = 0, EPI_VT = 1, EPI_RESID = 2, EPI_RELU = 3 };

__device__ __forceinline__ void stage4(const u16* __restrict__ Ahi, const u16* __restrict__ Alo,
                                       const u16* __restrict__ Bhi, const u16* __restrict__ Blo,
                                       int m0, int n0, int K, int k0,
                                       u16* buf, int tid, int w) {
  #pragma unroll
  for (int rnd = 0; rnd < 2; rnd++) {
    const int cid = rnd * 256 + tid;
    const int r = cid >> 2;
    const int lc = (cid & 3) ^ ((r >> 1) & 3);   // inverse swizzle on source (rule 21)
    const size_t asrc = (size_t)(m0 + r) * K + k0 + lc * 8;
    const size_t bsrc = (size_t)(n0 + r) * K + k0 + lc * 8;
    u16* dst = buf + rnd * 2048 + w * 512;       // wave-uniform dest, lanes linear
    gload_lds16(Ahi + asrc, dst);
    gload_lds16(Alo + asrc, dst + 4096);
    gload_lds16(Bhi + bsrc, dst + 8192);
    gload_lds16(Blo + bsrc, dst + 12288);
  }
}

template <int EPI>
__global__ __launch_bounds__(256, 2)
void k_gemm(const u16* __restrict__ Ahi, const u16* __restrict__ Alo,
            const u16* __restrict__ Bhi, const u16* __restrict__ Blo,
            const float* __restrict__ bias, int M, int N, int K,
            float* __restrict__ outf, const float* __restrict__ resid,
            u16* __restrict__ ohi, u16* __restrict__ olo) {
  __shared__ u16 lds[32768];   // 2 x [Ahi|Alo|Bhi|Blo], each 128x32 u16 (64KB total)
  const int tid = threadIdx.x;
  const int lane = tid & 63;
  const int w = tid >> 6, wr = w >> 1, wc = w & 1;
  const int r5 = lane & 31, g = lane >> 5;

  // XCD-chunked swizzle (grids %8==0) + 4x4 supertiles (~4MB working set / XCD L2)
  const int nwg = gridDim.x;
  const int cpx = nwg >> 3;
  const int bid = blockIdx.x;
  const int lid = (bid & 7) * cpx + (bid >> 3);
  const int GN = N >> 7;
  const int stpr = GN >> 2;
  const int st = lid >> 4, wi = lid & 15;
  const int mb = (st / stpr) * 4 + (wi >> 2);
  const int nb = (st % stpr) * 4 + (wi & 3);
  const int m0 = mb * 128, n0 = nb * 128;

  f32x16 acc[2][2];
  #pragma unroll
  for (int a = 0; a < 2; a++)
    #pragma unroll
    for (int b = 0; b < 2; b++)
      #pragma unroll
      for (int e = 0; e < 16; e++) acc[a][b][e] = 0.f;

  const int NT = K >> 5;
  stage4(Ahi, Alo, Bhi, Blo, m0, n0, K, 0, lds, tid, w);

  for (int it = 0; it < NT; ++it) {
    const int cur = it & 1;
    u16* bufc = lds + cur * 16384;
    if (it + 1 < NT) {
      stage4(Ahi, Alo, Bhi, Blo, m0, n0, K, (it + 1) << 5, lds + (cur ^ 1) * 16384, tid, w);
      asm volatile("s_waitcnt vmcnt(8)" ::: "memory");
    } else {
      asm volatile("s_waitcnt vmcnt(0)" ::: "memory");
    }
    __builtin_amdgcn_s_barrier();
    __builtin_amdgcn_sched_barrier(0);

    bf16x8 ah[2][2], al[2][2], bh[2][2], bl[2][2];
    #pragma unroll
    for (int mt = 0; mt < 2; mt++) {
      const int row = wr * 64 + mt * 32 + r5;
      #pragma unroll
      for (int t = 0; t < 2; t++) {
        const int off = row * 32 + (((t * 2 + g) ^ ((row >> 1) & 3)) << 3);
        ah[mt][t] = *reinterpret_cast<const bf16x8*>(&bufc[off]);
        al[mt][t] = *reinterpret_cast<const bf16x8*>(&bufc[4096 + off]);
      }
    }
    #pragma unroll
    for (int nt = 0; nt < 2; nt++) {
      const int col = wc * 64 + nt * 32 + r5;
      #pragma unroll
      for (int t = 0; t < 2; t++) {
        const int off = col * 32 + (((t * 2 + g) ^ ((col >> 1) & 3)) << 3);
        bh[nt][t] = *reinterpret_cast<const bf16x8*>(&bufc[8192 + off]);
        bl[nt][t] = *reinterpret_cast<const bf16x8*>(&bufc[12288 + off]);
      }
    }
    #pragma unroll
    for (int mt = 0; mt < 2; mt++)
      #pragma unroll
      for (int nt = 0; nt < 2; nt++)
        #pragma unroll
        for (int t = 0; t < 2; t++) {
          acc[mt][nt] = __builtin_amdgcn_mfma_f32_32x32x16_bf16(ah[mt][t], bh[nt][t], acc[mt][nt], 0, 0, 0);
          acc[mt][nt] = __builtin_amdgcn_mfma_f32_32x32x16_bf16(ah[mt][t], bl[nt][t], acc[mt][nt], 0, 0, 0);
          acc[mt][nt] = __builtin_amdgcn_mfma_f32_32x32x16_bf16(al[mt][t], bh[nt][t], acc[mt][nt], 0, 0, 0);
        }
    __builtin_amdgcn_s_barrier();
  }

  // epilogue; 32x32 C layout: col = lane&31, row = (r&3) + 8*(r>>2) + 4*(lane>>5)
  #pragma unroll
  for (int nt = 0; nt < 2; nt++) {
    const int gcol = n0 + wc * 64 + nt * 32 + r5;
    const float bv = bias[gcol];
    #pragma unroll
    for (int mt = 0; mt < 2; mt++) {
      #pragma unroll
      for (int r = 0; r < 16; r++) {
        const int grow = m0 + wr * 64 + mt * 32 + (r & 3) + ((r >> 2) << 3) + (g << 2);
        float v = acc[mt][nt][r] + bv;
        if constexpr (EPI == EPI_RESID) {
          const size_t o = (size_t)grow * N + gcol;
          outf[o] = v + resid[o];
        } else if constexpr (EPI == EPI_RELU) {
          v = fmaxf(v, 0.0f);
          const size_t o = (size_t)grow * N + gcol;
          const u16 h = f2bf(v);
          ohi[o] = h; olo[o] = f2bf(v - bf2f(h));
        } else {
          const int b = grow >> 11, s = grow & 2047;
          const int hh = gcol >> 6, d = gcol & 63;
          size_t o;
          if constexpr (EPI == EPI_QK)
            o = ((size_t)(b * HEADS + hh) * SEQ + s) * DEPTH + d;   // [BH][S][64]
          else
            o = ((size_t)(b * HEADS + hh) * DEPTH + d) * SEQ + s;   // V^T: [BH][64][S]
          const u16 h = f2bf(v);
          ohi[o] = h; olo[o] = f2bf(v - bf2f(h));
        }
      }
    }
  }
}

// ---------------- flash attention, bf16x2-split QK^T and PV ----------------
// P transport: P^T[kv][16 q] per wave (kv-row = 32B; the [64][16] layout IS the
// [16 subtiles][4 kv][16 q] form tr_b16 wants). Write: lane's 4 q-values per ct are
// contiguous -> 8 x ds_write_b64. Read: lane addr = subtile_base + l15*8B (slot-
// addressed); tr delivers column q=l15, elems j = 4 consecutive kv rows; 2 tr per
// 8-kv fragment.
__device__ __forceinline__ void stage_tile64(const u16* __restrict__ src, int gstride,
                                             u16* ldsbase, int tid) {
  #pragma unroll
  for (int i = 0; i < 2; i++) {
    const int c = i * 256 + tid;
    const int r = c >> 3;
    const int q = (c & 7) ^ (r & 7);
    gload_lds16(src + (size_t)r * gstride + q * 8,
                ldsbase + ((i * 256 + (tid & 192)) << 3));
  }
}

__global__ __launch_bounds__(256, 2)
void k_attn(const u16* __restrict__ qh, const u16* __restrict__ ql,
            const u16* __restrict__ kh, const u16* __restrict__ kl,
            const u16* __restrict__ vh, const u16* __restrict__ vl,
            u16* __restrict__ ch, u16* __restrict__ cl) {
  __shared__ u16 lds[2 * 16384 + 8192];
  const int tid = threadIdx.x, lane = tid & 63, w = tid >> 6;
  const int l15 = lane & 15, g = lane >> 4;
  const int bh = blockIdx.y;
  const int b = bh >> 4, hd = bh & 15;
  const int q0 = blockIdx.x * 64 + w * 16;
  u16* myp = lds + 2 * 16384 + w * 2048;   // P^T hi [0..1023] | lo [1024..2047]

  const size_t khead = (size_t)bh * (SEQ * DEPTH);
  const size_t vhead = (size_t)bh * (DEPTH * SEQ);

  bf16x8 qfh[2], qfl[2];
  #pragma unroll
  for (int t = 0; t < 2; t++) {
    const size_t qi = ((size_t)bh * SEQ + q0 + l15) * DEPTH + t * 32 + g * 8;
    qfh[t] = *reinterpret_cast<const bf16x8*>(&qh[qi]);
    qfl[t] = *reinterpret_cast<const bf16x8*>(&ql[qi]);
  }

  f32x4 o[4];
  #pragma unroll
  for (int dt = 0; dt < 4; dt++)
    #pragma unroll
    for (int e = 0; e < 4; e++) o[dt][e] = 0.f;
  float m_run[4] = {-1e30f, -1e30f, -1e30f, -1e30f};
  float l_run[4] = {0.f, 0.f, 0.f, 0.f};

  stage_tile64(kh + khead, DEPTH, lds,         tid);
  stage_tile64(kl + khead, DEPTH, lds + 4096,  tid);
  stage_tile64(vh + vhead, SEQ,   lds + 8192,  tid);
  stage_tile64(vl + vhead, SEQ,   lds + 12288, tid);

  const int NT = SEQ / 64;
  for (int it = 0; it < NT; ++it) {
    const int cur = it & 1;
    if (it + 1 < NT) {
      u16* Bn = lds + (cur ^ 1) * 16384;
      const size_t ko = khead + (size_t)(it + 1) * 64 * DEPTH;
      const size_t vo = vhead + (size_t)(it + 1) * 64;
      stage_tile64(kh + ko, DEPTH, Bn,         tid);
      stage_tile64(kl + ko, DEPTH, Bn + 4096,  tid);
      stage_tile64(vh + vo, SEQ,   Bn + 8192,  tid);
      stage_tile64(vl + vo, SEQ,   Bn + 12288, tid);
      asm volatile("s_waitcnt vmcnt(8)" ::: "memory");
    } else {
      asm volatile("s_waitcnt vmcnt(0)" ::: "memory");
    }
    __builtin_amdgcn_s_barrier();
    __builtin_amdgcn_sched_barrier(0);

    const u16* Kh = lds + cur * 16384;
    const u16* Kl = Kh + 4096;
    const u16* Vh = Kh + 8192;
    const u16* Vl = Kh + 12288;

    // QK^T: S[q=16][kv=64]
    f32x4 s[4];
    #pragma unroll
    for (int ct = 0; ct < 4; ct++) {
      f32x4 sa;
      #pragma unroll
      for (int e = 0; e < 4; e++) sa[e] = 0.f;
      const int row = ct * 16 + l15;
      #pragma unroll
      for (int t = 0; t < 2; t++) {
        const int idx = row * 64 + ((t * 32 + g * 8) ^ ((row & 7) << 3));
        const bf16x8 kfh = *reinterpret_cast<const bf16x8*>(&Kh[idx]);
        const bf16x8 kfl = *reinterpret_cast<const bf16x8*>(&Kl[idx]);
        sa = __builtin_amdgcn_mfma_f32_16x16x32_bf16(qfh[t], kfh, sa, 0, 0, 0);
        sa = __builtin_amdgcn_mfma_f32_16x16x32_bf16(qfh[t], kfl, sa, 0, 0, 0);
        sa = __builtin_amdgcn_mfma_f32_16x16x32_bf16(qfl[t], kfh, sa, 0, 0, 0);
      }
      s[ct] = sa;
    }

    // online softmax; C layout row(q) = g*4+j, col(kv) = ct*16+l15
    float p[4][4];
    #pragma unroll
    for (int j = 0; j < 4; j++) {
      float mx = fmaxf(fmaxf(s[0][j], s[1][j]), fmaxf(s[2][j], s[3][j])) * 0.125f;
      mx = rmax16(mx);
      const float mn = fmaxf(m_run[j], mx);
      const float alpha = __expf(m_run[j] - mn);
      m_run[j] = mn;
      float ls = 0.f;
      #pragma unroll
      for (int ct = 0; ct < 4; ct++) {
        const float pv = __expf(s[ct][j] * 0.125f - mn);
        p[ct][j] = pv; ls += pv;
      }
      ls = rsum16(ls);
      l_run[j] = l_run[j] * alpha + ls;
      #pragma unroll
      for (int dt = 0; dt < 4; dt++) o[dt][j] *= alpha;
    }

    // P^T packed hi/lo: 8 x ds_write_b64 (element (kv,q) at kv*16+q)
    #pragma unroll
    for (int ct = 0; ct < 4; ct++) {
      u16 hq[4], lq[4];
      #pragma unroll
      for (int j = 0; j < 4; j++) {
        hq[j] = f2bf(p[ct][j]);
        lq[j] = f2bf(p[ct][j] - bf2f(hq[j]));
      }
      const int base = (ct * 16 + l15) * 16 + g * 4;
      uint2 wh, wl;
      wh.x = (uint32_t)hq[0] | ((uint32_t)hq[1] << 16);
      wh.y = (uint32_t)hq[2] | ((uint32_t)hq[3] << 16);
      wl.x = (uint32_t)lq[0] | ((uint32_t)lq[1] << 16);
      wl.y = (uint32_t)lq[2] | ((uint32_t)lq[3] << 16);
      *reinterpret_cast<uint2*>(&myp[base]) = wh;
      *reinterpret_cast<uint2*>(&myp[1024 + base]) = wl;
    }
    asm volatile("s_waitcnt lgkmcnt(0)" ::: "memory");
    __builtin_amdgcn_sched_barrier(0);

    // A-fragment readback via tr: lane addr = subtile_base + l15*8B (slot-addressed).
    // Subtile for fragment t, group g starts at kv = t*32+g*8 -> element (t*32+g*8)*16;
    // tr #1 gives kv +0..3 (col q=l15), tr #2 at +64 elems (next 128B subtile) kv +4..7.
    bf16x8 pah[2], pal[2];
    #pragma unroll
    for (int t = 0; t < 2; t++) {
      const int e = (t * 32 + g * 8) * 16 + l15 * 4;
      union { uint2 u2[2]; bf16x8 v; } ah_, al_;
      ah_.u2[0] = tr_b64(&myp[e]);
      ah_.u2[1] = tr_b64(&myp[e + 64]);
      al_.u2[0] = tr_b64(&myp[1024 + e]);
      al_.u2[1] = tr_b64(&myp[1024 + e + 64]);
      pah[t] = ah_.v; pal[t] = al_.v;
    }
    asm volatile("s_waitcnt lgkmcnt(0)" ::: "memory");
    __builtin_amdgcn_sched_barrier(0);

    // PV: B-operand = V^T rows (d) from swizzled LDS
    #pragma unroll
    for (int dt = 0; dt < 4; dt++) {
      const int row = dt * 16 + l15;
      #pragma unroll
      for (int t = 0; t < 2; t++) {
        const int idx = row * 64 + ((t * 32 + g * 8) ^ ((row & 7) << 3));
        const bf16x8 vfh = *reinterpret_cast<const bf16x8*>(&Vh[idx]);
        const bf16x8 vfl = *reinterpret_cast<const bf16x8*>(&Vl[idx]);
        o[dt] = __builtin_amdgcn_mfma_f32_16x16x32_bf16(pah[t], vfh, o[dt], 0, 0, 0);
        o[dt] = __builtin_amdgcn_mfma_f32_16x16x32_bf16(pah[t], vfl, o[dt], 0, 0, 0);
        o[dt] = __builtin_amdgcn_mfma_f32_16x16x32_bf16(pal[t], vfh, o[dt], 0, 0, 0);
      }
    }
    __builtin_amdgcn_s_barrier();
  }

  #pragma unroll
  for (int j = 0; j < 4; j++) {
    const float inv = 1.0f / l_run[j];
    const int srow = q0 + g * 4 + j;
    #pragma unroll
    for (int dt = 0; dt < 4; dt++) {
      const float v = o[dt][j] * inv;
      const size_t oo = ((size_t)(b * SEQ + srow)) * DM + hd * 64 + dt * 16 + l15;
      const u16 h = f2bf(v);
      ch[oo] = h; cl[oo] = f2bf(v - bf2f(h));
    }
  }
}

// ---------------- LayerNorm (one row per block), optional split output ----------------
template <bool SPLIT>
__global__ __launch_bounds__(256)
void k_ln(const float* __restrict__ x, const float* __restrict__ gam,
          const float* __restrict__ bet, float* __restrict__ outf,
          u16* __restrict__ ohi, u16* __restrict__ olo) {
  const int row = blockIdx.x, tid = threadIdx.x, lane = tid & 63, w = tid >> 6;
  __shared__ float r1[4], r2[4];
  const float4 v = reinterpret_cast<const float4*>(x + (size_t)row * DM)[tid];
  float s = v.x + v.y + v.z + v.w;
  #pragma unroll
  for (int m = 1; m < 64; m <<= 1) s += __shfl_xor(s, m);
  if (lane == 0) r1[w] = s;
  __syncthreads();
  const float mu = (r1[0] + r1[1] + r1[2] + r1[3]) * (1.0f / DM);
  float4 c; c.x = v.x - mu; c.y = v.y - mu; c.z = v.z - mu; c.w = v.w - mu;
  float q = c.x * c.x + c.y * c.y + c.z * c.z + c.w * c.w;
  #pragma unroll
  for (int m = 1; m < 64; m <<= 1) q += __shfl_xor(q, m);
  if (lane == 0) r2[w] = q;
  __syncthreads();
  const float var = (r2[0] + r2[1] + r2[2] + r2[3]) * (1.0f / DM);
  const float rs = rsqrtf(var + 1e-6f);
  const float4 g4 = reinterpret_cast<const float4*>(gam)[tid];
  const float4 b4 = reinterpret_cast<const float4*>(bet)[tid];
  float4 o;
  o.x = c.x * rs * g4.x + b4.x;
  o.y = c.y * rs * g4.y + b4.y;
  o.z = c.z * rs * g4.z + b4.z;
  o.w = c.w * rs * g4.w + b4.w;
  reinterpret_cast<float4*>(outf + (size_t)row * DM)[tid] = o;
  if constexpr (SPLIT) {
    ushort4 h, l;
    h.x = f2bf(o.x); l.x = f2bf(o.x - bf2f(h.x));
    h.y = f2bf(o.y); l.y = f2bf(o.y - bf2f(h.y));
    h.z = f2bf(o.z); l.z = f2bf(o.z - bf2f(h.z));
    h.w = f2bf(o.w); l.w = f2bf(o.w - bf2f(h.w));
    reinterpret_cast<ushort4*>(ohi + (size_t)row * DM)[tid] = h;
    reinterpret_cast<ushort4*>(olo + (size_t)row * DM)[tid] = l;
  }
}

extern "C" void kernel_launch(void* const* d_in, const int* in_sizes, int n_in,
                              void* d_out, int out_size, void* d_ws, size_t ws_size,
                              hipStream_t stream) {
  const float* x   = (const float*)d_in[0];
  const float* wq  = (const float*)d_in[1];
  const float* bq  = (const float*)d_in[2];
  const float* wk  = (const float*)d_in[3];
  const float* bk  = (const float*)d_in[4];
  const float* wv  = (const float*)d_in[5];
  const float* bv  = (const float*)d_in[6];
  const float* wo  = (const float*)d_in[7];
  const float* bo  = (const float*)d_in[8];
  const float* w1  = (const float*)d_in[9];
  const float* b1  = (const float*)d_in[10];
  const float* w2  = (const float*)d_in[11];
  const float* b2  = (const float*)d_in[12];
  const float* g1  = (const float*)d_in[13];
  const float* be1 = (const float*)d_in[14];
  const float* g2  = (const float*)d_in[15];
  const float* be2 = (const float*)d_in[16];
  float* out = (float*)d_out;
  char* ws = (char*)d_ws;
  const size_t MB = (size_t)1 << 20;
  if (ws_size < 160 * MB) return;

  u16* wqt_h = (u16*)(ws + 0 * MB);   u16* wqt_l = (u16*)(ws + 2 * MB);
  u16* wkt_h = (u16*)(ws + 4 * MB);   u16* wkt_l = (u16*)(ws + 6 * MB);
  u16* wvt_h = (u16*)(ws + 8 * MB);   u16* wvt_l = (u16*)(ws + 10 * MB);
  u16* wot_h = (u16*)(ws + 12 * MB);  u16* wot_l = (u16*)(ws + 14 * MB);
  u16* w1t_h = (u16*)(ws + 16 * MB);  u16* w1t_l = (u16*)(ws + 24 * MB);
  u16* w2t_h = (u16*)(ws + 32 * MB);  u16* w2t_l = (u16*)(ws + 40 * MB);
  u16* xh  = (u16*)(ws + 48 * MB);    u16* xl  = (u16*)(ws + 56 * MB);
  u16* qh_ = (u16*)(ws + 64 * MB);    u16* ql_ = (u16*)(ws + 72 * MB);
  u16* kh_ = (u16*)(ws + 80 * MB);    u16* kl_ = (u16*)(ws + 88 * MB);
  u16* vh_ = (u16*)(ws + 96 * MB);    u16* vl_ = (u16*)(ws + 104 * MB);
  u16* hh_ = (u16*)(ws + 48 * MB);    u16* hl_ = (u16*)(ws + 80 * MB);
  u16* cth = (u16*)(ws + 112 * MB);   u16* ctl = (u16*)(ws + 120 * MB);
  u16* o1h = (u16*)(ws + 112 * MB);   u16* o1l = (u16*)(ws + 120 * MB);
  float* y   = (float*)(ws + 128 * MB);
  float* o1f = (float*)(ws + 144 * MB);

  k_split<<<4096, 256, 0, stream>>>(x, xh, xl, MROWS * DM / 4);
  k_tsplit<<<dim3(32, 32),  256, 0, stream>>>(wq, wqt_h, wqt_l, DM, DM);
  k_tsplit<<<dim3(32, 32),  256, 0, stream>>>(wk, wkt_h, wkt_l, DM, DM);
  k_tsplit<<<dim3(32, 32),  256, 0, stream>>>(wv, wvt_h, wvt_l, DM, DM);
  k_tsplit<<<dim3(32, 32),  256, 0, stream>>>(wo, wot_h, wot_l, DM, DM);
  k_tsplit<<<dim3(128, 32), 256, 0, stream>>>(w1, w1t_h, w1t_l, DM, DFF);
  k_tsplit<<<dim3(32, 128), 256, 0, stream>>>(w2, w2t_h, w2t_l, DFF, DM);

  k_gemm<EPI_QK><<<256, 256, 0, stream>>>(xh, xl, wqt_h, wqt_l, bq, MROWS, DM, DM, nullptr, nullptr, qh_, ql_);
  k_gemm<EPI_QK><<<256, 256, 0, stream>>>(xh, xl, wkt_h, wkt_l, bk, MROWS, DM, DM, nullptr, nullptr, kh_, kl_);
  k_gemm<EPI_VT><<<256, 256, 0, stream>>>(xh, xl, wvt_h, wvt_l, bv, MROWS, DM, DM, nullptr, nullptr, vh_, vl_);

  k_attn<<<dim3(32, 32), 256, 0, stream>>>(qh_, ql_, kh_, kl_, vh_, vl_, cth, ctl);

  k_gemm<EPI_RESID><<<256, 256, 0, stream>>>(cth, ctl, wot_h, wot_l, bo, MROWS, DM, DM, y, x, nullptr, nullptr);
  k_ln<true><<<MROWS, 256, 0, stream>>>(y, g1, be1, o1f, o1h, o1l);

  k_gemm<EPI_RELU><<<1024, 256, 0, stream>>>(o1h, o1l, w1t_h, w1t_l, b1, MROWS, DFF, DM, nullptr, nullptr, hh_, hl_);
  k_gemm<EPI_RESID><<<256, 256, 0, stream>>>(hh_, hl_, w2t_h, w2t_l, b2, MROWS, DM, DFF, y, o1f, nullptr, nullptr);
  k_ln<false><<<MROWS, 256, 0, stream>>>(y, g2, be2, out, nullptr, nullptr);
}

// Round 8
// 584.694 us; speedup vs baseline: 1.9990x; 1.0977x over previous
//
#include <hip/hip_runtime.h>
#include <stdint.h>

// Transformer block, fp32 in/out. GEMMs: bf16x2-split MFMA (hi+lo, 3 products).
// R7 (resubmit; R7 bench was an infra timeout): attention switched to single-product
// fp16 MFMA (error ~2^-11, fits threshold with margin): 16 vs 48 MFMA/iter, LDS
// 80->40KB (4 blocks/CU), P transport halved. QKV GEMM epilogues emit fp16 Q/K/V^T;
// all other kernels unchanged from R6.

#define DM    1024
#define SEQ   2048
#define HEADS 16
#define DEPTH 64
#define DFF   4096
#define MROWS 4096   // B*S

typedef __bf16 bf16x8 __attribute__((ext_vector_type(8)));
typedef _Float16 h16x8 __attribute__((ext_vector_type(8)));
typedef float  f32x4  __attribute__((ext_vector_type(4)));
typedef float  f32x16 __attribute__((ext_vector_type(16)));
typedef unsigned short u16;

__device__ __forceinline__ u16 f2bf(float f) {
  __bf16 h = (__bf16)f;          // RNE
  u16 r; __builtin_memcpy(&r, &h, 2); return r;
}
__device__ __forceinline__ float bf2f(u16 h) {
  return __uint_as_float(((uint32_t)h) << 16);
}
__device__ __forceinline__ u16 f2h(float f) {
  _Float16 h = (_Float16)f;      // RNE v_cvt_f16_f32
  u16 r; __builtin_memcpy(&r, &h, 2); return r;
}

__device__ __forceinline__ void gload_lds16(const u16* g, u16* l) {
  __builtin_amdgcn_global_load_lds(
      (const __attribute__((address_space(1))) uint32_t*)g,
      (__attribute__((address_space(3))) uint32_t*)l, 16, 0, 0);
}

// DPP row_ror all-reduce over the lane's 16-lane row (VALU pipe, no DS traffic)
template <int N>
__device__ __forceinline__ float dppror(float x) {
  return __int_as_float(__builtin_amdgcn_update_dpp(
      0, __float_as_int(x), 0x120 | N, 0xF, 0xF, true));
}
__device__ __forceinline__ float rmax16(float v) {
  v = fmaxf(v, dppror<8>(v)); v = fmaxf(v, dppror<4>(v));
  v = fmaxf(v, dppror<2>(v)); v = fmaxf(v, dppror<1>(v));
  return v;
}
__device__ __forceinline__ float rsum16(float v) {
  v += dppror<8>(v); v += dppror<4>(v); v += dppror<2>(v); v += dppror<1>(v);
  return v;
}

// ds_read_b64_tr_b16 (per-lane gather, slot-addressed): byte addr = W*128 + s*8
// -> elem j delivered from LDS elem W*64 + s + j*16 (slot s = column of the
// window's 4x16 tile). Verified R6.
__device__ __forceinline__ uint2 tr_b64(const u16* p) {
  uint2 r;
  asm volatile("ds_read_b64_tr_b16 %0, %1"
               : "=v"(r)
               : "v"((const __attribute__((address_space(3))) u16*)p)
               : "memory");
  return r;
}

// ---------------- split fp32 -> bf16 hi/lo ----------------
__global__ void k_split(const float* __restrict__ x, u16* __restrict__ hi,
                        u16* __restrict__ lo, int n4) {
  int i = blockIdx.x * 256 + threadIdx.x;
  if (i >= n4) return;
  float4 v = reinterpret_cast<const float4*>(x)[i];
  ushort4 h, l;
  h.x = f2bf(v.x); l.x = f2bf(v.x - bf2f(h.x));
  h.y = f2bf(v.y); l.y = f2bf(v.y - bf2f(h.y));
  h.z = f2bf(v.z); l.z = f2bf(v.z - bf2f(h.z));
  h.w = f2bf(v.w); l.w = f2bf(v.w - bf2f(h.w));
  reinterpret_cast<ushort4*>(hi)[i] = h;
  reinterpret_cast<ushort4*>(lo)[i] = l;
}

// ---------------- transpose + split: in[K][N] fp32 -> out[N][K] bf16 hi/lo ----------------
__global__ void k_tsplit(const float* __restrict__ in, u16* __restrict__ oh,
                         u16* __restrict__ ol, int K, int N) {
  __shared__ float t[32][33];
  const int tx = threadIdx.x & 31, ty = threadIdx.x >> 5;
  const int c0 = blockIdx.x * 32, r0 = blockIdx.y * 32;
  #pragma unroll
  for (int i = 0; i < 4; i++)
    t[ty + 8 * i][tx] = in[(size_t)(r0 + ty + 8 * i) * N + c0 + tx];
  __syncthreads();
  #pragma unroll
  for (int i = 0; i < 4; i++) {
    const int n = c0 + ty + 8 * i, k = r0 + tx;
    const float v = t[tx][ty + 8 * i];
    const u16 h = f2bf(v);
    oh[(size_t)n * K + k] = h;
    ol[(size_t)n * K + k] = f2bf(v - bf2f(h));
  }
}

// ---------------- split GEMM: C = A[M,K] @ B^T[N,K] + bias, bf16x2 operands ----------------
// EPI_QK / EPI_VT emit SINGLE fp16 (attention consumes fp16).
enum { EPI_QK = 0, EPI_VT = 1, EPI_RESID = 2, EPI_RELU = 3 };

__device__ __forceinline__ void stage4(const u16* __restrict__ Ahi, const u16* __restrict__ Alo,
                                       const u16* __restrict__ Bhi, const u16* __restrict__ Blo,
                                       int m0, int n0, int K, int k0,
                                       u16* buf, int tid, int w) {
  #pragma unroll
  for (int rnd = 0; rnd < 2; rnd++) {
    const int cid = rnd * 256 + tid;
    const int r = cid >> 2;
    const int lc = (cid & 3) ^ ((r >> 1) & 3);   // inverse swizzle on source (rule 21)
    const size_t asrc = (size_t)(m0 + r) * K + k0 + lc * 8;
    const size_t bsrc = (size_t)(n0 + r) * K + k0 + lc * 8;
    u16* dst = buf + rnd * 2048 + w * 512;       // wave-uniform dest, lanes linear
    gload_lds16(Ahi + asrc, dst);
    gload_lds16(Alo + asrc, dst + 4096);
    gload_lds16(Bhi + bsrc, dst + 8192);
    gload_lds16(Blo + bsrc, dst + 12288);
  }
}

template <int EPI>
__global__ __launch_bounds__(256, 2)
void k_gemm(const u16* __restrict__ Ahi, const u16* __restrict__ Alo,
            const u16* __restrict__ Bhi, const u16* __restrict__ Blo,
            const float* __restrict__ bias, int M, int N, int K,
            float* __restrict__ outf, const float* __restrict__ resid,
            u16* __restrict__ ohi, u16* __restrict__ olo) {
  __shared__ u16 lds[32768];   // 2 x [Ahi|Alo|Bhi|Blo], each 128x32 u16 (64KB total)
  const int tid = threadIdx.x;
  const int lane = tid & 63;
  const int w = tid >> 6, wr = w >> 1, wc = w & 1;
  const int r5 = lane & 31, g = lane >> 5;

  // XCD-chunked swizzle (grids %8==0) + 4x4 supertiles (~4MB working set / XCD L2)
  const int nwg = gridDim.x;
  const int cpx = nwg >> 3;
  const int bid = blockIdx.x;
  const int lid = (bid & 7) * cpx + (bid >> 3);
  const int GN = N >> 7;
  const int stpr = GN >> 2;
  const int st = lid >> 4, wi = lid & 15;
  const int mb = (st / stpr) * 4 + (wi >> 2);
  const int nb = (st % stpr) * 4 + (wi & 3);
  const int m0 = mb * 128, n0 = nb * 128;

  f32x16 acc[2][2];
  #pragma unroll
  for (int a = 0; a < 2; a++)
    #pragma unroll
    for (int b = 0; b < 2; b++)
      #pragma unroll
      for (int e = 0; e < 16; e++) acc[a][b][e] = 0.f;

  const int NT = K >> 5;
  stage4(Ahi, Alo, Bhi, Blo, m0, n0, K, 0, lds, tid, w);

  for (int it = 0; it < NT; ++it) {
    const int cur = it & 1;
    u16* bufc = lds + cur * 16384;
    if (it + 1 < NT) {
      stage4(Ahi, Alo, Bhi, Blo, m0, n0, K, (it + 1) << 5, lds + (cur ^ 1) * 16384, tid, w);
      asm volatile("s_waitcnt vmcnt(8)" ::: "memory");
    } else {
      asm volatile("s_waitcnt vmcnt(0)" ::: "memory");
    }
    __builtin_amdgcn_s_barrier();
    __builtin_amdgcn_sched_barrier(0);

    bf16x8 ah[2][2], al[2][2], bh[2][2], bl[2][2];
    #pragma unroll
    for (int mt = 0; mt < 2; mt++) {
      const int row = wr * 64 + mt * 32 + r5;
      #pragma unroll
      for (int t = 0; t < 2; t++) {
        const int off = row * 32 + (((t * 2 + g) ^ ((row >> 1) & 3)) << 3);
        ah[mt][t] = *reinterpret_cast<const bf16x8*>(&bufc[off]);
        al[mt][t] = *reinterpret_cast<const bf16x8*>(&bufc[4096 + off]);
      }
    }
    #pragma unroll
    for (int nt = 0; nt < 2; nt++) {
      const int col = wc * 64 + nt * 32 + r5;
      #pragma unroll
      for (int t = 0; t < 2; t++) {
        const int off = col * 32 + (((t * 2 + g) ^ ((col >> 1) & 3)) << 3);
        bh[nt][t] = *reinterpret_cast<const bf16x8*>(&bufc[8192 + off]);
        bl[nt][t] = *reinterpret_cast<const bf16x8*>(&bufc[12288 + off]);
      }
    }
    #pragma unroll
    for (int mt = 0; mt < 2; mt++)
      #pragma unroll
      for (int nt = 0; nt < 2; nt++)
        #pragma unroll
        for (int t = 0; t < 2; t++) {
          acc[mt][nt] = __builtin_amdgcn_mfma_f32_32x32x16_bf16(ah[mt][t], bh[nt][t], acc[mt][nt], 0, 0, 0);
          acc[mt][nt] = __builtin_amdgcn_mfma_f32_32x32x16_bf16(ah[mt][t], bl[nt][t], acc[mt][nt], 0, 0, 0);
          acc[mt][nt] = __builtin_amdgcn_mfma_f32_32x32x16_bf16(al[mt][t], bh[nt][t], acc[mt][nt], 0, 0, 0);
        }
    __builtin_amdgcn_s_barrier();
  }

  // epilogue; 32x32 C layout: col = lane&31, row = (r&3) + 8*(r>>2) + 4*(lane>>5)
  #pragma unroll
  for (int nt = 0; nt < 2; nt++) {
    const int gcol = n0 + wc * 64 + nt * 32 + r5;
    const float bv = bias[gcol];
    #pragma unroll
    for (int mt = 0; mt < 2; mt++) {
      #pragma unroll
      for (int r = 0; r < 16; r++) {
        const int grow = m0 + wr * 64 + mt * 32 + (r & 3) + ((r >> 2) << 3) + (g << 2);
        float v = acc[mt][nt][r] + bv;
        if constexpr (EPI == EPI_RESID) {
          const size_t o = (size_t)grow * N + gcol;
          outf[o] = v + resid[o];
        } else if constexpr (EPI == EPI_RELU) {
          v = fmaxf(v, 0.0f);
          const size_t o = (size_t)grow * N + gcol;
          const u16 h = f2bf(v);
          ohi[o] = h; olo[o] = f2bf(v - bf2f(h));
        } else {
          const int b = grow >> 11, s = grow & 2047;
          const int hh = gcol >> 6, d = gcol & 63;
          size_t o;
          if constexpr (EPI == EPI_QK)
            o = ((size_t)(b * HEADS + hh) * SEQ + s) * DEPTH + d;   // [BH][S][64]
          else
            o = ((size_t)(b * HEADS + hh) * DEPTH + d) * SEQ + s;   // V^T: [BH][64][S]
          ohi[o] = f2h(v);   // single fp16 for attention
        }
      }
    }
  }
}

// ---------------- flash attention, single-product fp16 QK^T and PV ----------------
// K/V staged fp16 (8KB each), double-buffered (32KB) + 4 waves x 2KB P^T = 40KB LDS
// -> 4 blocks/CU. P^T [64 kv][16 q] fp16; write 4 x ds_write_b64, read 4 x tr_b64.
__device__ __forceinline__ void stage_tile64(const u16* __restrict__ src, int gstride,
                                             u16* ldsbase, int tid) {
  #pragma unroll
  for (int i = 0; i < 2; i++) {
    const int c = i * 256 + tid;
    const int r = c >> 3;
    const int q = (c & 7) ^ (r & 7);
    gload_lds16(src + (size_t)r * gstride + q * 8,
                ldsbase + ((i * 256 + (tid & 192)) << 3));
  }
}

__global__ __launch_bounds__(256, 4)
void k_attn(const u16* __restrict__ qh, const u16* __restrict__ kh,
            const u16* __restrict__ vh,
            u16* __restrict__ ch, u16* __restrict__ cl) {
  __shared__ u16 lds[2 * 8192 + 4096];   // 2 x [K|V] + 4 x 1024 P^T  (40KB)
  const int tid = threadIdx.x, lane = tid & 63, w = tid >> 6;
  const int l15 = lane & 15, g = lane >> 4;
  const int bh = blockIdx.y;
  const int b = bh >> 4, hd = bh & 15;
  const int q0 = blockIdx.x * 64 + w * 16;
  u16* myp = lds + 2 * 8192 + w * 1024;   // P^T fp16 [64][16]

  const size_t khead = (size_t)bh * (SEQ * DEPTH);
  const size_t vhead = (size_t)bh * (DEPTH * SEQ);

  h16x8 qf[2];
  #pragma unroll
  for (int t = 0; t < 2; t++) {
    const size_t qi = ((size_t)bh * SEQ + q0 + l15) * DEPTH + t * 32 + g * 8;
    qf[t] = *reinterpret_cast<const h16x8*>(&qh[qi]);
  }

  f32x4 o[4];
  #pragma unroll
  for (int dt = 0; dt < 4; dt++)
    #pragma unroll
    for (int e = 0; e < 4; e++) o[dt][e] = 0.f;
  float m_run[4] = {-1e30f, -1e30f, -1e30f, -1e30f};
  float l_run[4] = {0.f, 0.f, 0.f, 0.f};

  stage_tile64(kh + khead, DEPTH, lds,        tid);
  stage_tile64(vh + vhead, SEQ,   lds + 4096, tid);

  const int NT = SEQ / 64;
  for (int it = 0; it < NT; ++it) {
    const int cur = it & 1;
    if (it + 1 < NT) {
      u16* Bn = lds + (cur ^ 1) * 8192;
      const size_t ko = khead + (size_t)(it + 1) * 64 * DEPTH;
      const size_t vo = vhead + (size_t)(it + 1) * 64;
      stage_tile64(kh + ko, DEPTH, Bn,        tid);
      stage_tile64(vh + vo, SEQ,   Bn + 4096, tid);
      asm volatile("s_waitcnt vmcnt(4)" ::: "memory");   // current tile's 4 done
    } else {
      asm volatile("s_waitcnt vmcnt(0)" ::: "memory");
    }
    __builtin_amdgcn_s_barrier();
    __builtin_amdgcn_sched_barrier(0);

    const u16* Kt = lds + cur * 8192;
    const u16* Vt = Kt + 4096;

    // QK^T: S[q=16][kv=64]
    f32x4 s[4];
    #pragma unroll
    for (int ct = 0; ct < 4; ct++) {
      f32x4 sa;
      #pragma unroll
      for (int e = 0; e < 4; e++) sa[e] = 0.f;
      const int row = ct * 16 + l15;
      #pragma unroll
      for (int t = 0; t < 2; t++) {
        const int idx = row * 64 + ((t * 32 + g * 8) ^ ((row & 7) << 3));
        const h16x8 kf = *reinterpret_cast<const h16x8*>(&Kt[idx]);
        sa = __builtin_amdgcn_mfma_f32_16x16x32_f16(qf[t], kf, sa, 0, 0, 0);
      }
      s[ct] = sa;
    }

    // online softmax; C layout row(q) = g*4+j, col(kv) = ct*16+l15
    float p[4][4];
    #pragma unroll
    for (int j = 0; j < 4; j++) {
      float mx = fmaxf(fmaxf(s[0][j], s[1][j]), fmaxf(s[2][j], s[3][j])) * 0.125f;
      mx = rmax16(mx);
      const float mn = fmaxf(m_run[j], mx);
      const float alpha = __expf(m_run[j] - mn);
      m_run[j] = mn;
      float ls = 0.f;
      #pragma unroll
      for (int ct = 0; ct < 4; ct++) {
        const float pv = __expf(s[ct][j] * 0.125f - mn);
        p[ct][j] = pv; ls += pv;
      }
      ls = rsum16(ls);
      l_run[j] = l_run[j] * alpha + ls;
      #pragma unroll
      for (int dt = 0; dt < 4; dt++) o[dt][j] *= alpha;
    }

    // P^T fp16: 4 x ds_write_b64 (element (kv,q) at kv*16+q)
    #pragma unroll
    for (int ct = 0; ct < 4; ct++) {
      u16 hq[4];
      #pragma unroll
      for (int j = 0; j < 4; j++) hq[j] = f2h(p[ct][j]);
      const int base = (ct * 16 + l15) * 16 + g * 4;
      uint2 wh;
      wh.x = (uint32_t)hq[0] | ((uint32_t)hq[1] << 16);
      wh.y = (uint32_t)hq[2] | ((uint32_t)hq[3] << 16);
      *reinterpret_cast<uint2*>(&myp[base]) = wh;
    }
    asm volatile("s_waitcnt lgkmcnt(0)" ::: "memory");
    __builtin_amdgcn_sched_barrier(0);

    // A-fragment readback via tr: lane addr = subtile_base + l15*8B (slot = column q).
    h16x8 pa[2];
    #pragma unroll
    for (int t = 0; t < 2; t++) {
      const int e = (t * 32 + g * 8) * 16 + l15 * 4;
      union { uint2 u2[2]; h16x8 v; } a_;
      a_.u2[0] = tr_b64(&myp[e]);
      a_.u2[1] = tr_b64(&myp[e + 64]);
      pa[t] = a_.v;
    }
    asm volatile("s_waitcnt lgkmcnt(0)" ::: "memory");
    __builtin_amdgcn_sched_barrier(0);

    // PV: B-operand = V^T rows (d) from swizzled LDS
    #pragma unroll
    for (int dt = 0; dt < 4; dt++) {
      const int row = dt * 16 + l15;
      #pragma unroll
      for (int t = 0; t < 2; t++) {
        const int idx = row * 64 + ((t * 32 + g * 8) ^ ((row & 7) << 3));
        const h16x8 vf = *reinterpret_cast<const h16x8*>(&Vt[idx]);
        o[dt] = __builtin_amdgcn_mfma_f32_16x16x32_f16(pa[t], vf, o[dt], 0, 0, 0);
      }
    }
    __builtin_amdgcn_s_barrier();
  }

  #pragma unroll
  for (int j = 0; j < 4; j++) {
    const float inv = 1.0f / l_run[j];
    const int srow = q0 + g * 4 + j;
    #pragma unroll
    for (int dt = 0; dt < 4; dt++) {
      const float v = o[dt][j] * inv;
      const size_t oo = ((size_t)(b * SEQ + srow)) * DM + hd * 64 + dt * 16 + l15;
      const u16 h = f2bf(v);
      ch[oo] = h; cl[oo] = f2bf(v - bf2f(h));
    }
  }
}

// ---------------- LayerNorm (one row per block), optional split output ----------------
template <bool SPLIT>
__global__ __launch_bounds__(256)
void k_ln(const float* __restrict__ x, const float* __restrict__ gam,
          const float* __restrict__ bet, float* __restrict__ outf,
          u16* __restrict__ ohi, u16* __restrict__ olo) {
  const int row = blockIdx.x, tid = threadIdx.x, lane = tid & 63, w = tid >> 6;
  __shared__ float r1[4], r2[4];
  const float4 v = reinterpret_cast<const float4*>(x + (size_t)row * DM)[tid];
  float s = v.x + v.y + v.z + v.w;
  #pragma unroll
  for (int m = 1; m < 64; m <<= 1) s += __shfl_xor(s, m);
  if (lane == 0) r1[w] = s;
  __syncthreads();
  const float mu = (r1[0] + r1[1] + r1[2] + r1[3]) * (1.0f / DM);
  float4 c; c.x = v.x - mu; c.y = v.y - mu; c.z = v.z - mu; c.w = v.w - mu;
  float q = c.x * c.x + c.y * c.y + c.z * c.z + c.w * c.w;
  #pragma unroll
  for (int m = 1; m < 64; m <<= 1) q += __shfl_xor(q, m);
  if (lane == 0) r2[w] = q;
  __syncthreads();
  const float var = (r2[0] + r2[1] + r2[2] + r2[3]) * (1.0f / DM);
  const float rs = rsqrtf(var + 1e-6f);
  const float4 g4 = reinterpret_cast<const float4*>(gam)[tid];
  const float4 b4 = reinterpret_cast<const float4*>(bet)[tid];
  float4 o;
  o.x = c.x * rs * g4.x + b4.x;
  o.y = c.y * rs * g4.y + b4.y;
  o.z = c.z * rs * g4.z + b4.z;
  o.w = c.w * rs * g4.w + b4.w;
  reinterpret_cast<float4*>(outf + (size_t)row * DM)[tid] = o;
  if constexpr (SPLIT) {
    ushort4 h, l;
    h.x = f2bf(o.x); l.x = f2bf(o.x - bf2f(h.x));
    h.y = f2bf(o.y); l.y = f2bf(o.y - bf2f(h.y));
    h.z = f2bf(o.z); l.z = f2bf(o.z - bf2f(h.z));
    h.w = f2bf(o.w); l.w = f2bf(o.w - bf2f(h.w));
    reinterpret_cast<ushort4*>(ohi + (size_t)row * DM)[tid] = h;
    reinterpret_cast<ushort4*>(olo + (size_t)row * DM)[tid] = l;
  }
}

extern "C" void kernel_launch(void* const* d_in, const int* in_sizes, int n_in,
                              void* d_out, int out_size, void* d_ws, size_t ws_size,
                              hipStream_t stream) {
  const float* x   = (const float*)d_in[0];
  const float* wq  = (const float*)d_in[1];
  const float* bq  = (const float*)d_in[2];
  const float* wk  = (const float*)d_in[3];
  const float* bk  = (const float*)d_in[4];
  const float* wv  = (const float*)d_in[5];
  const float* bv  = (const float*)d_in[6];
  const float* wo  = (const float*)d_in[7];
  const float* bo  = (const float*)d_in[8];
  const float* w1  = (const float*)d_in[9];
  const float* b1  = (const float*)d_in[10];
  const float* w2  = (const float*)d_in[11];
  const float* b2  = (const float*)d_in[12];
  const float* g1  = (const float*)d_in[13];
  const float* be1 = (const float*)d_in[14];
  const float* g2  = (const float*)d_in[15];
  const float* be2 = (const float*)d_in[16];
  float* out = (float*)d_out;
  char* ws = (char*)d_ws;
  const size_t MB = (size_t)1 << 20;
  if (ws_size < 160 * MB) return;

  u16* wqt_h = (u16*)(ws + 0 * MB);   u16* wqt_l = (u16*)(ws + 2 * MB);
  u16* wkt_h = (u16*)(ws + 4 * MB);   u16* wkt_l = (u16*)(ws + 6 * MB);
  u16* wvt_h = (u16*)(ws + 8 * MB);   u16* wvt_l = (u16*)(ws + 10 * MB);
  u16* wot_h = (u16*)(ws + 12 * MB);  u16* wot_l = (u16*)(ws + 14 * MB);
  u16* w1t_h = (u16*)(ws + 16 * MB);  u16* w1t_l = (u16*)(ws + 24 * MB);
  u16* w2t_h = (u16*)(ws + 32 * MB);  u16* w2t_l = (u16*)(ws + 40 * MB);
  u16* xh  = (u16*)(ws + 48 * MB);    u16* xl  = (u16*)(ws + 56 * MB);
  u16* qh_ = (u16*)(ws + 64 * MB);    // fp16 Q [BH][S][64]
  u16* kh_ = (u16*)(ws + 80 * MB);    // fp16 K [BH][S][64]
  u16* vh_ = (u16*)(ws + 96 * MB);    // fp16 V^T [BH][64][S]
  u16* hh_ = (u16*)(ws + 48 * MB);    u16* hl_ = (u16*)(ws + 80 * MB);
  u16* cth = (u16*)(ws + 112 * MB);   u16* ctl = (u16*)(ws + 120 * MB);
  u16* o1h = (u16*)(ws + 112 * MB);   u16* o1l = (u16*)(ws + 120 * MB);
  float* y   = (float*)(ws + 128 * MB);
  float* o1f = (float*)(ws + 144 * MB);

  k_split<<<4096, 256, 0, stream>>>(x, xh, xl, MROWS * DM / 4);
  k_tsplit<<<dim3(32, 32),  256, 0, stream>>>(wq, wqt_h, wqt_l, DM, DM);
  k_tsplit<<<dim3(32, 32),  256, 0, stream>>>(wk, wkt_h, wkt_l, DM, DM);
  k_tsplit<<<dim3(32, 32),  256, 0, stream>>>(wv, wvt_h, wvt_l, DM, DM);
  k_tsplit<<<dim3(32, 32),  256, 0, stream>>>(wo, wot_h, wot_l, DM, DM);
  k_tsplit<<<dim3(128, 32), 256, 0, stream>>>(w1, w1t_h, w1t_l, DM, DFF);
  k_tsplit<<<dim3(32, 128), 256, 0, stream>>>(w2, w2t_h, w2t_l, DFF, DM);

  k_gemm<EPI_QK><<<256, 256, 0, stream>>>(xh, xl, wqt_h, wqt_l, bq, MROWS, DM, DM, nullptr, nullptr, qh_, nullptr);
  k_gemm<EPI_QK><<<256, 256, 0, stream>>>(xh, xl, wkt_h, wkt_l, bk, MROWS, DM, DM, nullptr, nullptr, kh_, nullptr);
  k_gemm<EPI_VT><<<256, 256, 0, stream>>>(xh, xl, wvt_h, wvt_l, bv, MROWS, DM, DM, nullptr, nullptr, vh_, nullptr);

  k_attn<<<dim3(32, 32), 256, 0, stream>>>(qh_, kh_, vh_, cth, ctl);

  k_gemm<EPI_RESID><<<256, 256, 0, stream>>>(cth, ctl, wot_h, wot_l, bo, MROWS, DM, DM, y, x, nullptr, nullptr);
  k_ln<true><<<MROWS, 256, 0, stream>>>(y, g1, be1, o1f, o1h, o1l);

  k_gemm<EPI_RELU><<<1024, 256, 0, stream>>>(o1h, o1l, w1t_h, w1t_l, b1, MROWS, DFF, DM, nullptr, nullptr, hh_, hl_);
  k_gemm<EPI_RESID><<<256, 256, 0, stream>>>(hh_, hl_, w2t_h, w2t_l, b2, MROWS, DM, DFF, y, o1f, nullptr, nullptr);
  k_ln<false><<<MROWS, 256, 0, stream>>>(y, g2, be2, out, nullptr, nullptr);
}

// Round 9
// 408.154 us; speedup vs baseline: 2.8636x; 1.4325x over previous
//
#include <hip/hip_runtime.h>
#include <stdint.h>

// Transformer block, fp32 in/out. R9: ALL matmuls single-product fp16 MFMA
// (mfma_f32_32x32x16_f16, fp32 accumulate). Rationale: bf16x3 GEMM measured at
// 862 TF = the 128^2 2-phase structural ceiling; fp16 single-product is 3x less
// MFMA work AND more accurate than any 2-product bf16 variant (2^-11 vs 2^-8 rel).
// Residual adds + LayerNorm stay fp32. Attention unchanged from R8 (fp16, verified).

#define DM    1024
#define SEQ   2048
#define HEADS 16
#define DEPTH 64
#define DFF   4096
#define MROWS 4096   // B*S

typedef _Float16 h16x8 __attribute__((ext_vector_type(8)));
typedef float  f32x4  __attribute__((ext_vector_type(4)));
typedef float  f32x16 __attribute__((ext_vector_type(16)));
typedef unsigned short u16;

__device__ __forceinline__ u16 f2bf(float f) {
  __bf16 h = (__bf16)f;          // RNE
  u16 r; __builtin_memcpy(&r, &h, 2); return r;
}
__device__ __forceinline__ u16 f2h(float f) {
  _Float16 h = (_Float16)f;      // RNE v_cvt_f16_f32
  u16 r; __builtin_memcpy(&r, &h, 2); return r;
}

__device__ __forceinline__ void gload_lds16(const u16* g, u16* l) {
  __builtin_amdgcn_global_load_lds(
      (const __attribute__((address_space(1))) uint32_t*)g,
      (__attribute__((address_space(3))) uint32_t*)l, 16, 0, 0);
}

// DPP row_ror all-reduce over the lane's 16-lane row (VALU pipe, no DS traffic)
template <int N>
__device__ __forceinline__ float dppror(float x) {
  return __int_as_float(__builtin_amdgcn_update_dpp(
      0, __float_as_int(x), 0x120 | N, 0xF, 0xF, true));
}
__device__ __forceinline__ float rmax16(float v) {
  v = fmaxf(v, dppror<8>(v)); v = fmaxf(v, dppror<4>(v));
  v = fmaxf(v, dppror<2>(v)); v = fmaxf(v, dppror<1>(v));
  return v;
}
__device__ __forceinline__ float rsum16(float v) {
  v += dppror<8>(v); v += dppror<4>(v); v += dppror<2>(v); v += dppror<1>(v);
  return v;
}

// ds_read_b64_tr_b16 (per-lane gather, slot-addressed; verified R6): byte addr =
// W*128 + s*8 -> elem j delivered from LDS elem W*64 + s + j*16.
__device__ __forceinline__ uint2 tr_b64(const u16* p) {
  uint2 r;
  asm volatile("ds_read_b64_tr_b16 %0, %1"
               : "=v"(r)
               : "v"((const __attribute__((address_space(3))) u16*)p)
               : "memory");
  return r;
}

// ---------------- fp32 -> fp16 cast (vectorized) ----------------
__global__ void k_split(const float* __restrict__ x, u16* __restrict__ oh, int n4) {
  int i = blockIdx.x * 256 + threadIdx.x;
  if (i >= n4) return;
  float4 v = reinterpret_cast<const float4*>(x)[i];
  ushort4 h;
  h.x = f2h(v.x); h.y = f2h(v.y); h.z = f2h(v.z); h.w = f2h(v.w);
  reinterpret_cast<ushort4*>(oh)[i] = h;
}

// ---------------- transpose + cast: in[K][N] fp32 -> out[N][K] fp16 ----------------
__global__ void k_tsplit(const float* __restrict__ in, u16* __restrict__ oh,
                         int K, int N) {
  __shared__ float t[32][33];
  const int tx = threadIdx.x & 31, ty = threadIdx.x >> 5;
  const int c0 = blockIdx.x * 32, r0 = blockIdx.y * 32;
  #pragma unroll
  for (int i = 0; i < 4; i++)
    t[ty + 8 * i][tx] = in[(size_t)(r0 + ty + 8 * i) * N + c0 + tx];
  __syncthreads();
  #pragma unroll
  for (int i = 0; i < 4; i++) {
    const int n = c0 + ty + 8 * i, k = r0 + tx;
    oh[(size_t)n * K + k] = f2h(t[tx][ty + 8 * i]);
  }
}

// ---------------- fp16 GEMM: C = A[M,K] @ B^T[N,K] + bias ----------------
// 128x128 tile, BK=32, 4 waves (64x64/wave = 2x2 of mfma_f32_32x32x16_f16).
// Tiles [128][32] u16; swizzle: stored chunk = logical ^ ((row>>1)&3) -> 8
// consecutive rows hit 8 distinct 16B granules (conflict-free b128, verified R3).
// Double-buffered, counted vmcnt(4) + raw barriers (T4).
enum { EPI_QK = 0, EPI_VT = 1, EPI_RESID = 2, EPI_RELU = 3 };

__device__ __forceinline__ void stage2(const u16* __restrict__ A, const u16* __restrict__ B,
                                       int m0, int n0, int K, int k0,
                                       u16* buf, int tid, int w) {
  #pragma unroll
  for (int rnd = 0; rnd < 2; rnd++) {
    const int cid = rnd * 256 + tid;
    const int r = cid >> 2;
    const int lc = (cid & 3) ^ ((r >> 1) & 3);   // inverse swizzle on source (rule 21)
    u16* dst = buf + rnd * 2048 + w * 512;       // wave-uniform dest, lanes linear
    gload_lds16(A + (size_t)(m0 + r) * K + k0 + lc * 8, dst);
    gload_lds16(B + (size_t)(n0 + r) * K + k0 + lc * 8, dst + 4096);
  }
}

template <int EPI>
__global__ __launch_bounds__(256, 4)
void k_gemm(const u16* __restrict__ A, const u16* __restrict__ B,
            const float* __restrict__ bias, int M, int N, int K,
            float* __restrict__ outf, const float* __restrict__ resid,
            u16* __restrict__ oh) {
  __shared__ u16 lds[16384];   // 2 x [A|B], each 128x32 u16 (32KB total)
  const int tid = threadIdx.x;
  const int lane = tid & 63;
  const int w = tid >> 6, wr = w >> 1, wc = w & 1;
  const int r5 = lane & 31, g = lane >> 5;

  // XCD-chunked swizzle (grids %8==0) + 4x4 supertiles for L2 locality (T1)
  const int nwg = gridDim.x;
  const int cpx = nwg >> 3;
  const int bid = blockIdx.x;
  const int lid = (bid & 7) * cpx + (bid >> 3);
  const int GN = N >> 7;
  const int stpr = GN >> 2;
  const int st = lid >> 4, wi = lid & 15;
  const int mb = (st / stpr) * 4 + (wi >> 2);
  const int nb = (st % stpr) * 4 + (wi & 3);
  const int m0 = mb * 128, n0 = nb * 128;

  f32x16 acc[2][2];
  #pragma unroll
  for (int a = 0; a < 2; a++)
    #pragma unroll
    for (int b = 0; b < 2; b++)
      #pragma unroll
      for (int e = 0; e < 16; e++) acc[a][b][e] = 0.f;

  const int NT = K >> 5;
  stage2(A, B, m0, n0, K, 0, lds, tid, w);

  for (int it = 0; it < NT; ++it) {
    const int cur = it & 1;
    u16* bufc = lds + cur * 8192;
    if (it + 1 < NT) {
      stage2(A, B, m0, n0, K, (it + 1) << 5, lds + (cur ^ 1) * 8192, tid, w);
      asm volatile("s_waitcnt vmcnt(4)" ::: "memory");   // current tile's 4 done
    } else {
      asm volatile("s_waitcnt vmcnt(0)" ::: "memory");
    }
    __builtin_amdgcn_s_barrier();
    __builtin_amdgcn_sched_barrier(0);

    h16x8 af[2][2], bf[2][2];
    #pragma unroll
    for (int mt = 0; mt < 2; mt++) {
      const int row = wr * 64 + mt * 32 + r5;
      #pragma unroll
      for (int t = 0; t < 2; t++) {
        const int off = row * 32 + (((t * 2 + g) ^ ((row >> 1) & 3)) << 3);
        af[mt][t] = *reinterpret_cast<const h16x8*>(&bufc[off]);
      }
    }
    #pragma unroll
    for (int nt = 0; nt < 2; nt++) {
      const int col = wc * 64 + nt * 32 + r5;
      #pragma unroll
      for (int t = 0; t < 2; t++) {
        const int off = col * 32 + (((t * 2 + g) ^ ((col >> 1) & 3)) << 3);
        bf[nt][t] = *reinterpret_cast<const h16x8*>(&bufc[4096 + off]);
      }
    }
    #pragma unroll
    for (int mt = 0; mt < 2; mt++)
      #pragma unroll
      for (int nt = 0; nt < 2; nt++)
        #pragma unroll
        for (int t = 0; t < 2; t++)
          acc[mt][nt] = __builtin_amdgcn_mfma_f32_32x32x16_f16(af[mt][t], bf[nt][t], acc[mt][nt], 0, 0, 0);
    __builtin_amdgcn_s_barrier();
  }

  // epilogue; 32x32 C layout: col = lane&31, row = (r&3) + 8*(r>>2) + 4*(lane>>5)
  #pragma unroll
  for (int nt = 0; nt < 2; nt++) {
    const int gcol = n0 + wc * 64 + nt * 32 + r5;
    const float bv = bias[gcol];
    #pragma unroll
    for (int mt = 0; mt < 2; mt++) {
      #pragma unroll
      for (int r = 0; r < 16; r++) {
        const int grow = m0 + wr * 64 + mt * 32 + (r & 3) + ((r >> 2) << 3) + (g << 2);
        float v = acc[mt][nt][r] + bv;
        if constexpr (EPI == EPI_RESID) {
          const size_t o = (size_t)grow * N + gcol;
          outf[o] = v + resid[o];
        } else if constexpr (EPI == EPI_RELU) {
          const size_t o = (size_t)grow * N + gcol;
          oh[o] = f2h(fmaxf(v, 0.0f));
        } else {
          const int b = grow >> 11, s = grow & 2047;
          const int hh = gcol >> 6, d = gcol & 63;
          size_t o;
          if constexpr (EPI == EPI_QK)
            o = ((size_t)(b * HEADS + hh) * SEQ + s) * DEPTH + d;   // [BH][S][64]
          else
            o = ((size_t)(b * HEADS + hh) * DEPTH + d) * SEQ + s;   // V^T: [BH][64][S]
          oh[o] = f2h(v);
        }
      }
    }
  }
}

// ---------------- flash attention, fp16 (verified R8); ctx out now fp16 ----------------
__device__ __forceinline__ void stage_tile64(const u16* __restrict__ src, int gstride,
                                             u16* ldsbase, int tid) {
  #pragma unroll
  for (int i = 0; i < 2; i++) {
    const int c = i * 256 + tid;
    const int r = c >> 3;
    const int q = (c & 7) ^ (r & 7);
    gload_lds16(src + (size_t)r * gstride + q * 8,
                ldsbase + ((i * 256 + (tid & 192)) << 3));
  }
}

__global__ __launch_bounds__(256, 4)
void k_attn(const u16* __restrict__ qh, const u16* __restrict__ kh,
            const u16* __restrict__ vh, u16* __restrict__ ch) {
  __shared__ u16 lds[2 * 8192 + 4096];   // 2 x [K|V] + 4 x 1024 P^T  (40KB)
  const int tid = threadIdx.x, lane = tid & 63, w = tid >> 6;
  const int l15 = lane & 15, g = lane >> 4;
  const int bh = blockIdx.y;
  const int b = bh >> 4, hd = bh & 15;
  const int q0 = blockIdx.x * 64 + w * 16;
  u16* myp = lds + 2 * 8192 + w * 1024;   // P^T fp16 [64][16]

  const size_t khead = (size_t)bh * (SEQ * DEPTH);
  const size_t vhead = (size_t)bh * (DEPTH * SEQ);

  h16x8 qf[2];
  #pragma unroll
  for (int t = 0; t < 2; t++) {
    const size_t qi = ((size_t)bh * SEQ + q0 + l15) * DEPTH + t * 32 + g * 8;
    qf[t] = *reinterpret_cast<const h16x8*>(&qh[qi]);
  }

  f32x4 o[4];
  #pragma unroll
  for (int dt = 0; dt < 4; dt++)
    #pragma unroll
    for (int e = 0; e < 4; e++) o[dt][e] = 0.f;
  float m_run[4] = {-1e30f, -1e30f, -1e30f, -1e30f};
  float l_run[4] = {0.f, 0.f, 0.f, 0.f};

  stage_tile64(kh + khead, DEPTH, lds,        tid);
  stage_tile64(vh + vhead, SEQ,   lds + 4096, tid);

  const int NT = SEQ / 64;
  for (int it = 0; it < NT; ++it) {
    const int cur = it & 1;
    if (it + 1 < NT) {
      u16* Bn = lds + (cur ^ 1) * 8192;
      const size_t ko = khead + (size_t)(it + 1) * 64 * DEPTH;
      const size_t vo = vhead + (size_t)(it + 1) * 64;
      stage_tile64(kh + ko, DEPTH, Bn,        tid);
      stage_tile64(vh + vo, SEQ,   Bn + 4096, tid);
      asm volatile("s_waitcnt vmcnt(4)" ::: "memory");
    } else {
      asm volatile("s_waitcnt vmcnt(0)" ::: "memory");
    }
    __builtin_amdgcn_s_barrier();
    __builtin_amdgcn_sched_barrier(0);

    const u16* Kt = lds + cur * 8192;
    const u16* Vt = Kt + 4096;

    f32x4 s[4];
    #pragma unroll
    for (int ct = 0; ct < 4; ct++) {
      f32x4 sa;
      #pragma unroll
      for (int e = 0; e < 4; e++) sa[e] = 0.f;
      const int row = ct * 16 + l15;
      #pragma unroll
      for (int t = 0; t < 2; t++) {
        const int idx = row * 64 + ((t * 32 + g * 8) ^ ((row & 7) << 3));
        const h16x8 kf = *reinterpret_cast<const h16x8*>(&Kt[idx]);
        sa = __builtin_amdgcn_mfma_f32_16x16x32_f16(qf[t], kf, sa, 0, 0, 0);
      }
      s[ct] = sa;
    }

    float p[4][4];
    #pragma unroll
    for (int j = 0; j < 4; j++) {
      float mx = fmaxf(fmaxf(s[0][j], s[1][j]), fmaxf(s[2][j], s[3][j])) * 0.125f;
      mx = rmax16(mx);
      const float mn = fmaxf(m_run[j], mx);
      const float alpha = __expf(m_run[j] - mn);
      m_run[j] = mn;
      float ls = 0.f;
      #pragma unroll
      for (int ct = 0; ct < 4; ct++) {
        const float pv = __expf(s[ct][j] * 0.125f - mn);
        p[ct][j] = pv; ls += pv;
      }
      ls = rsum16(ls);
      l_run[j] = l_run[j] * alpha + ls;
      #pragma unroll
      for (int dt = 0; dt < 4; dt++) o[dt][j] *= alpha;
    }

    #pragma unroll
    for (int ct = 0; ct < 4; ct++) {
      u16 hq[4];
      #pragma unroll
      for (int j = 0; j < 4; j++) hq[j] = f2h(p[ct][j]);
      const int base = (ct * 16 + l15) * 16 + g * 4;
      uint2 wh;
      wh.x = (uint32_t)hq[0] | ((uint32_t)hq[1] << 16);
      wh.y = (uint32_t)hq[2] | ((uint32_t)hq[3] << 16);
      *reinterpret_cast<uint2*>(&myp[base]) = wh;
    }
    asm volatile("s_waitcnt lgkmcnt(0)" ::: "memory");
    __builtin_amdgcn_sched_barrier(0);

    h16x8 pa[2];
    #pragma unroll
    for (int t = 0; t < 2; t++) {
      const int e = (t * 32 + g * 8) * 16 + l15 * 4;
      union { uint2 u2[2]; h16x8 v; } a_;
      a_.u2[0] = tr_b64(&myp[e]);
      a_.u2[1] = tr_b64(&myp[e + 64]);
      pa[t] = a_.v;
    }
    asm volatile("s_waitcnt lgkmcnt(0)" ::: "memory");
    __builtin_amdgcn_sched_barrier(0);

    #pragma unroll
    for (int dt = 0; dt < 4; dt++) {
      const int row = dt * 16 + l15;
      #pragma unroll
      for (int t = 0; t < 2; t++) {
        const int idx = row * 64 + ((t * 32 + g * 8) ^ ((row & 7) << 3));
        const h16x8 vf = *reinterpret_cast<const h16x8*>(&Vt[idx]);
        o[dt] = __builtin_amdgcn_mfma_f32_16x16x32_f16(pa[t], vf, o[dt], 0, 0, 0);
      }
    }
    __builtin_amdgcn_s_barrier();
  }

  #pragma unroll
  for (int j = 0; j < 4; j++) {
    const float inv = 1.0f / l_run[j];
    const int srow = q0 + g * 4 + j;
    #pragma unroll
    for (int dt = 0; dt < 4; dt++) {
      const size_t oo = ((size_t)(b * SEQ + srow)) * DM + hd * 64 + dt * 16 + l15;
      ch[oo] = f2h(o[dt][j] * inv);   // fp16 ctx (Wo GEMM A-operand)
    }
  }
}

// ---------------- LayerNorm (one row per block), optional fp16 output ----------------
template <bool SPLIT>
__global__ __launch_bounds__(256)
void k_ln(const float* __restrict__ x, const float* __restrict__ gam,
          const float* __restrict__ bet, float* __restrict__ outf,
          u16* __restrict__ oh) {
  const int row = blockIdx.x, tid = threadIdx.x, lane = tid & 63, w = tid >> 6;
  __shared__ float r1[4], r2[4];
  const float4 v = reinterpret_cast<const float4*>(x + (size_t)row * DM)[tid];
  float s = v.x + v.y + v.z + v.w;
  #pragma unroll
  for (int m = 1; m < 64; m <<= 1) s += __shfl_xor(s, m);
  if (lane == 0) r1[w] = s;
  __syncthreads();
  const float mu = (r1[0] + r1[1] + r1[2] + r1[3]) * (1.0f / DM);
  float4 c; c.x = v.x - mu; c.y = v.y - mu; c.z = v.z - mu; c.w = v.w - mu;
  float q = c.x * c.x + c.y * c.y + c.z * c.z + c.w * c.w;
  #pragma unroll
  for (int m = 1; m < 64; m <<= 1) q += __shfl_xor(q, m);
  if (lane == 0) r2[w] = q;
  __syncthreads();
  const float var = (r2[0] + r2[1] + r2[2] + r2[3]) * (1.0f / DM);
  const float rs = rsqrtf(var + 1e-6f);
  const float4 g4 = reinterpret_cast<const float4*>(gam)[tid];
  const float4 b4 = reinterpret_cast<const float4*>(bet)[tid];
  float4 o;
  o.x = c.x * rs * g4.x + b4.x;
  o.y = c.y * rs * g4.y + b4.y;
  o.z = c.z * rs * g4.z + b4.z;
  o.w = c.w * rs * g4.w + b4.w;
  reinterpret_cast<float4*>(outf + (size_t)row * DM)[tid] = o;
  if constexpr (SPLIT) {
    ushort4 h;
    h.x = f2h(o.x); h.y = f2h(o.y); h.z = f2h(o.z); h.w = f2h(o.w);
    reinterpret_cast<ushort4*>(oh + (size_t)row * DM)[tid] = h;
  }
}

extern "C" void kernel_launch(void* const* d_in, const int* in_sizes, int n_in,
                              void* d_out, int out_size, void* d_ws, size_t ws_size,
                              hipStream_t stream) {
  const float* x   = (const float*)d_in[0];
  const float* wq  = (const float*)d_in[1];
  const float* bq  = (const float*)d_in[2];
  const float* wk  = (const float*)d_in[3];
  const float* bk  = (const float*)d_in[4];
  const float* wv  = (const float*)d_in[5];
  const float* bv  = (const float*)d_in[6];
  const float* wo  = (const float*)d_in[7];
  const float* bo  = (const float*)d_in[8];
  const float* w1  = (const float*)d_in[9];
  const float* b1  = (const float*)d_in[10];
  const float* w2  = (const float*)d_in[11];
  const float* b2  = (const float*)d_in[12];
  const float* g1  = (const float*)d_in[13];
  const float* be1 = (const float*)d_in[14];
  const float* g2  = (const float*)d_in[15];
  const float* be2 = (const float*)d_in[16];
  float* out = (float*)d_out;
  char* ws = (char*)d_ws;
  const size_t MB = (size_t)1 << 20;
  if (ws_size < 160 * MB) return;

  // workspace map (fp16 singles): total 136MB
  u16* wqt = (u16*)(ws + 0 * MB);
  u16* wkt = (u16*)(ws + 2 * MB);
  u16* wvt = (u16*)(ws + 4 * MB);
  u16* wot = (u16*)(ws + 6 * MB);
  u16* w1t = (u16*)(ws + 8 * MB);     // 8MB
  u16* w2t = (u16*)(ws + 16 * MB);    // 8MB
  u16* xh  = (u16*)(ws + 24 * MB);    // 8MB
  u16* qh_ = (u16*)(ws + 32 * MB);    // fp16 Q [BH][S][64]
  u16* kh_ = (u16*)(ws + 40 * MB);    // fp16 K [BH][S][64]
  u16* vh_ = (u16*)(ws + 48 * MB);    // fp16 V^T [BH][64][S]
  u16* cth = (u16*)(ws + 56 * MB);    // fp16 ctx [B*S][DM]
  u16* o1h = (u16*)(ws + 64 * MB);    // fp16 LN1 out
  u16* hh_ = (u16*)(ws + 72 * MB);    // fp16 relu hidden, 32MB
  float* y   = (float*)(ws + 104 * MB);
  float* o1f = (float*)(ws + 120 * MB);

  k_split<<<4096, 256, 0, stream>>>(x, xh, MROWS * DM / 4);
  k_tsplit<<<dim3(32, 32),  256, 0, stream>>>(wq, wqt, DM, DM);
  k_tsplit<<<dim3(32, 32),  256, 0, stream>>>(wk, wkt, DM, DM);
  k_tsplit<<<dim3(32, 32),  256, 0, stream>>>(wv, wvt, DM, DM);
  k_tsplit<<<dim3(32, 32),  256, 0, stream>>>(wo, wot, DM, DM);
  k_tsplit<<<dim3(128, 32), 256, 0, stream>>>(w1, w1t, DM, DFF);
  k_tsplit<<<dim3(32, 128), 256, 0, stream>>>(w2, w2t, DFF, DM);

  k_gemm<EPI_QK><<<256, 256, 0, stream>>>(xh, wqt, bq, MROWS, DM, DM, nullptr, nullptr, qh_);
  k_gemm<EPI_QK><<<256, 256, 0, stream>>>(xh, wkt, bk, MROWS, DM, DM, nullptr, nullptr, kh_);
  k_gemm<EPI_VT><<<256, 256, 0, stream>>>(xh, wvt, bv, MROWS, DM, DM, nullptr, nullptr, vh_);

  k_attn<<<dim3(32, 32), 256, 0, stream>>>(qh_, kh_, vh_, cth);

  k_gemm<EPI_RESID><<<256, 256, 0, stream>>>(cth, wot, bo, MROWS, DM, DM, y, x, nullptr);
  k_ln<true><<<MROWS, 256, 0, stream>>>(y, g1, be1, o1f, o1h);

  k_gemm<EPI_RELU><<<1024, 256, 0, stream>>>(o1h, w1t, b1, MROWS, DFF, DM, nullptr, nullptr, hh_);
  k_gemm<EPI_RESID><<<256, 256, 0, stream>>>(hh_, w2t, b2, MROWS, DM, DFF, y, o1f, nullptr);
  k_ln<false><<<MROWS, 256, 0, stream>>>(y, g2, be2, out, nullptr);
}